// Round 1
// baseline (1525.898 us; speedup 1.0000x reference)
//
#include <hip/hip_runtime.h>

#define NW 100000
#define NT 20000
#define ND 5000
#define EWW 1600000
#define EBU 1000000
#define ESE 1000000
#define ECR 20000

// ---------------- utility kernels ----------------

__global__ void k_zero(int* __restrict__ p, int n) {
    int t = blockIdx.x * blockDim.x + threadIdx.x;
    if (t < n) p[t] = 0;
}

// init out[r*64+c] = b0[c] (+ b1[c]) (+ b2[c])
__global__ __launch_bounds__(256) void k_init(float* __restrict__ out,
                                              const float* __restrict__ b0,
                                              const float* __restrict__ b1,
                                              const float* __restrict__ b2, int n64) {
    int tid = blockIdx.x * blockDim.x + threadIdx.x;
    if (tid >= n64) return;
    int c = tid & 63;
    float v = b0[c];
    if (b1) v += b1[c];
    if (b2) v += b2[c];
    out[tid] = v;
}

// ---------------- CSR build (4 edge lists in one pass each) ----------------

struct Edge4 {
    const int* src[4]; const int* dst[4];
    int* cnt[4]; int* cur[4]; int* srt[4];
    int E[4];
};

__global__ __launch_bounds__(256) void k_hist4(Edge4 a, int total) {
    int tid = blockIdx.x * blockDim.x + threadIdx.x;
    if (tid >= total) return;
    int li = 0, off = tid;
    while (li < 3 && off >= a.E[li]) { off -= a.E[li]; ++li; }
    atomicAdd(&a.cnt[li][a.dst[li][off]], 1);
}

__global__ __launch_bounds__(256) void k_fill4(Edge4 a, int total) {
    int tid = blockIdx.x * blockDim.x + threadIdx.x;
    if (tid >= total) return;
    int li = 0, off = tid;
    while (li < 3 && off >= a.E[li]) { off -= a.E[li]; ++li; }
    int d = a.dst[li][off];
    int p = atomicAdd(&a.cur[li][d], 1);
    a.srt[li][p] = a.src[li][off];
}

struct Scan4 { const int* cnt[4]; int* off[4]; int* cur[4]; int n[4]; };

// one block per array: exclusive scan of cnt -> off (and cur copy), off[n]=total
__global__ __launch_bounds__(1024) void k_scan4(Scan4 a) {
    int b = blockIdx.x;
    const int* cnt = a.cnt[b]; int* off = a.off[b]; int* cur = a.cur[b]; int n = a.n[b];
    __shared__ int sm[1024];
    int t = threadIdx.x;
    int chunk = (n + 1023) >> 10;
    int lo = t * chunk, hi = lo + chunk;
    if (hi > n) hi = n;
    if (lo > n) lo = n;
    int s = 0;
    for (int i = lo; i < hi; ++i) s += cnt[i];
    sm[t] = s;
    __syncthreads();
    for (int o = 1; o < 1024; o <<= 1) {
        int v = (t >= o) ? sm[t - o] : 0;
        __syncthreads();
        sm[t] += v;
        __syncthreads();
    }
    int run = sm[t] - s;  // exclusive prefix of this thread's chunk
    for (int i = lo; i < hi; ++i) {
        off[i] = run; cur[i] = run; run += cnt[i];
    }
    if (t == 1023) off[n] = sm[1023];
}

// ---------------- weight prep: wv = Wd @ a_d per relation ----------------

struct Wv6 { const float* Wd[6]; const float* ad[6]; int K[6]; };

__global__ __launch_bounds__(64) void k_wv(Wv6 a, float* __restrict__ wv) {
    int b = blockIdx.x, t = threadIdx.x;
    if (t < a.K[b]) {
        const float* Wd = a.Wd[b];
        const float* ad = a.ad[b];
        float s = 0.f;
        for (int j = 0; j < 64; ++j) s = fmaf(Wd[t * 64 + j], ad[j], s);
        wv[b * 64 + t] = s;
    }
}

// ---------------- src-side GEMM: hs = X@W [N,64], es = hs@a_s [N] ----------------

template <int K>
__global__ __launch_bounds__(256) void k_src(const float* __restrict__ X,
                                             const float* __restrict__ W,
                                             const float* __restrict__ as_,
                                             float* __restrict__ hs,
                                             float* __restrict__ es, int N) {
    int wid = (blockIdx.x * 256 + threadIdx.x) >> 6;
    int lane = threadIdx.x & 63;
    if (wid >= N) return;
    const float* xr = X + (size_t)wid * K;
    float xl = (lane < K) ? xr[lane] : 0.f;
    float acc = 0.f;
#pragma unroll
    for (int k = 0; k < K; ++k) {
        float xv = __shfl(xl, k, 64);
        acc = fmaf(xv, W[k * 64 + lane], acc);
    }
    hs[(size_t)wid * 64 + lane] = acc;
    float v = acc * as_[lane];
#pragma unroll
    for (int o = 32; o > 0; o >>= 1) v += __shfl_xor(v, o, 64);
    if (lane == 0) es[wid] = v;
}

// ---------------- pull aggregation: one wave per dst row ----------------
// ed fused: ed[j] = dot(Xd[j,:K], wv). out[j] += sum_e exp(e-m)*hs[src_e] / den

template <int K>
__global__ __launch_bounds__(256) void k_agg(const float* __restrict__ hs,
                                             const float* __restrict__ es,
                                             const float* __restrict__ Xd,
                                             const float* __restrict__ wv,
                                             const int* __restrict__ off,
                                             const int* __restrict__ srt,
                                             float* __restrict__ out, int Nd) {
    int wid = (blockIdx.x * 256 + threadIdx.x) >> 6;
    int lane = threadIdx.x & 63;
    if (wid >= Nd) return;
    int s0 = off[wid], s1 = off[wid + 1];
    if (s0 == s1) return;  // no incoming edges: out stays at bias init
    // ed for this dst row
    float p = (lane < K) ? Xd[(size_t)wid * K + lane] * wv[lane] : 0.f;
#pragma unroll
    for (int o = 32; o > 0; o >>= 1) p += __shfl_xor(p, o, 64);
    float edj = p;
    // sweep 1: cooperative max over edges
    float m = -3.4e38f;
    for (int i = s0 + lane; i < s1; i += 64) {
        float ev = es[srt[i]] + edj;
        ev = ev > 0.f ? ev : 0.2f * ev;
        m = fmaxf(m, ev);
    }
#pragma unroll
    for (int o = 32; o > 0; o >>= 1) m = fmaxf(m, __shfl_xor(m, o, 64));
    // sweep 2: serial edges, lane = channel
    float acc = 0.f, den = 0.f;
    int i = s0;
    for (; i + 1 < s1; i += 2) {
        int a0 = srt[i], a1 = srt[i + 1];
        float e0 = es[a0] + edj; e0 = e0 > 0.f ? e0 : 0.2f * e0;
        float e1 = es[a1] + edj; e1 = e1 > 0.f ? e1 : 0.2f * e1;
        float w0 = __expf(e0 - m), w1 = __expf(e1 - m);
        float h0 = hs[(size_t)a0 * 64 + lane];
        float h1 = hs[(size_t)a1 * 64 + lane];
        den += w0 + w1;
        acc = fmaf(w0, h0, acc);
        acc = fmaf(w1, h1, acc);
    }
    if (i < s1) {
        int a0 = srt[i];
        float e0 = es[a0] + edj; e0 = e0 > 0.f ? e0 : 0.2f * e0;
        float w0 = __expf(e0 - m);
        den += w0;
        acc = fmaf(w0, hs[(size_t)a0 * 64 + lane], acc);
    }
    out[(size_t)wid * 64 + lane] += acc / (den + 1e-16f);
}

// ---------------- final FC: out = t2 @ Wfc + bfc  [NT,2] ----------------

__global__ __launch_bounds__(256) void k_fc(const float* __restrict__ t2,
                                            const float* __restrict__ Wfc,
                                            const float* __restrict__ bfc,
                                            float* __restrict__ out, int N) {
    int wid = (blockIdx.x * 256 + threadIdx.x) >> 6;
    int lane = threadIdx.x & 63;
    if (wid >= N) return;
    float v = t2[(size_t)wid * 64 + lane];
    float p0 = v * Wfc[lane * 2 + 0];
    float p1 = v * Wfc[lane * 2 + 1];
#pragma unroll
    for (int o = 32; o > 0; o >>= 1) {
        p0 += __shfl_xor(p0, o, 64);
        p1 += __shfl_xor(p1, o, 64);
    }
    if (lane == 0) {
        out[wid * 2 + 0] = p0 + bfc[0];
        out[wid * 2 + 1] = p1 + bfc[1];
    }
}

// ---------------- launcher ----------------

extern "C" void kernel_launch(void* const* d_in, const int* in_sizes, int n_in,
                              void* d_out, int out_size, void* d_ws, size_t ws_size,
                              hipStream_t stream) {
    const float* xw = (const float*)d_in[0];
    const float* xt = (const float*)d_in[1];
    const float* xd = (const float*)d_in[2];
    // per-relation params: Ws, Wd, as, ad, b at base..base+4
    const float* g1ww_Ws = (const float*)d_in[3];
    const float* g1ww_Wd = (const float*)d_in[4];
    const float* g1ww_as = (const float*)d_in[5];
    const float* g1ww_ad = (const float*)d_in[6];
    const float* g1ww_b  = (const float*)d_in[7];
    const float* g1bu_Ws = (const float*)d_in[8];
    const float* g1bu_Wd = (const float*)d_in[9];
    const float* g1bu_as = (const float*)d_in[10];
    const float* g1bu_ad = (const float*)d_in[11];
    const float* g1bu_b  = (const float*)d_in[12];
    const float* g1se_Ws = (const float*)d_in[13];
    const float* g1se_Wd = (const float*)d_in[14];
    const float* g1se_as = (const float*)d_in[15];
    const float* g1se_ad = (const float*)d_in[16];
    const float* g1se_b  = (const float*)d_in[17];
    const float* g1cr_Ws = (const float*)d_in[18];
    const float* g1cr_Wd = (const float*)d_in[19];
    const float* g1cr_as = (const float*)d_in[20];
    const float* g1cr_ad = (const float*)d_in[21];
    const float* g1cr_b  = (const float*)d_in[22];
    // d_in[23..27] = g2ww params: w2 is dead code in the reference -> skipped
    const float* g2bu_Ws = (const float*)d_in[28];
    const float* g2bu_Wd = (const float*)d_in[29];
    const float* g2bu_as = (const float*)d_in[30];
    const float* g2bu_ad = (const float*)d_in[31];
    const float* g2bu_b  = (const float*)d_in[32];
    const float* g2se_Ws = (const float*)d_in[33];
    const float* g2se_Wd = (const float*)d_in[34];
    const float* g2se_as = (const float*)d_in[35];
    const float* g2se_ad = (const float*)d_in[36];
    const float* g2se_b  = (const float*)d_in[37];
    const float* Wfc = (const float*)d_in[38];
    const float* bfc = (const float*)d_in[39];
    const int* ww_src = (const int*)d_in[40];
    const int* ww_dst = (const int*)d_in[41];
    const int* bu_src = (const int*)d_in[42];
    const int* bu_dst = (const int*)d_in[43];
    const int* se_src = (const int*)d_in[44];
    const int* se_dst = (const int*)d_in[45];
    const int* cr_src = (const int*)d_in[46];
    const int* cr_dst = (const int*)d_in[47];

    // ---- workspace carve ----
    char* p = (char*)d_ws;
    auto alloc = [&](size_t bytes) {
        char* r = p;
        p += (bytes + 255) & ~(size_t)255;
        return r;
    };
    float* hs  = (float*)alloc((size_t)NW * 64 * 4);  // reused by every relation
    float* es  = (float*)alloc((size_t)NW * 4);
    float* w1  = (float*)alloc((size_t)NW * 64 * 4);
    float* t1  = (float*)alloc((size_t)NT * 64 * 4);
    float* t2  = (float*)alloc((size_t)NT * 64 * 4);
    float* wv  = (float*)alloc(6 * 64 * 4);
    int* cntW = (int*)alloc((size_t)(NW + 3 * NT) * 4);  // contiguous: W,B,S,C
    int* cntB = cntW + NW;
    int* cntS = cntB + NT;
    int* cntC = cntS + NT;
    int* offW = (int*)alloc((size_t)(NW + 1) * 4);
    int* offB = (int*)alloc((size_t)(NT + 1) * 4);
    int* offS = (int*)alloc((size_t)(NT + 1) * 4);
    int* offC = (int*)alloc((size_t)(NT + 1) * 4);
    int* curW = (int*)alloc((size_t)NW * 4);
    int* curB = (int*)alloc((size_t)NT * 4);
    int* curS = (int*)alloc((size_t)NT * 4);
    int* curC = (int*)alloc((size_t)NT * 4);
    int* srtW = (int*)alloc((size_t)EWW * 4);
    int* srtB = (int*)alloc((size_t)EBU * 4);
    int* srtS = (int*)alloc((size_t)ESE * 4);
    int* srtC = (int*)alloc((size_t)ECR * 4);

    const int thr = 256;
    const int totalE = EWW + EBU + ESE + ECR;

    // ---- CSR build for all 4 edge lists ----
    k_zero<<<(NW + 3 * NT + thr - 1) / thr, thr, 0, stream>>>(cntW, NW + 3 * NT);

    Edge4 ea;
    ea.src[0] = ww_src; ea.dst[0] = ww_dst; ea.cnt[0] = cntW; ea.cur[0] = curW; ea.srt[0] = srtW; ea.E[0] = EWW;
    ea.src[1] = bu_src; ea.dst[1] = bu_dst; ea.cnt[1] = cntB; ea.cur[1] = curB; ea.srt[1] = srtB; ea.E[1] = EBU;
    ea.src[2] = se_src; ea.dst[2] = se_dst; ea.cnt[2] = cntS; ea.cur[2] = curS; ea.srt[2] = srtS; ea.E[2] = ESE;
    ea.src[3] = cr_src; ea.dst[3] = cr_dst; ea.cnt[3] = cntC; ea.cur[3] = curC; ea.srt[3] = srtC; ea.E[3] = ECR;
    k_hist4<<<(totalE + thr - 1) / thr, thr, 0, stream>>>(ea, totalE);

    Scan4 sa;
    sa.cnt[0] = cntW; sa.off[0] = offW; sa.cur[0] = curW; sa.n[0] = NW;
    sa.cnt[1] = cntB; sa.off[1] = offB; sa.cur[1] = curB; sa.n[1] = NT;
    sa.cnt[2] = cntS; sa.off[2] = offS; sa.cur[2] = curS; sa.n[2] = NT;
    sa.cnt[3] = cntC; sa.off[3] = offC; sa.cur[3] = curC; sa.n[3] = NT;
    k_scan4<<<4, 1024, 0, stream>>>(sa);

    k_fill4<<<(totalE + thr - 1) / thr, thr, 0, stream>>>(ea, totalE);

    // ---- wv = Wd @ a_d for the 6 live relations ----
    Wv6 wa;
    wa.Wd[0] = g1ww_Wd; wa.ad[0] = g1ww_ad; wa.K[0] = 32;
    wa.Wd[1] = g1bu_Wd; wa.ad[1] = g1bu_ad; wa.K[1] = 32;
    wa.Wd[2] = g1se_Wd; wa.ad[2] = g1se_ad; wa.K[2] = 32;
    wa.Wd[3] = g1cr_Wd; wa.ad[3] = g1cr_ad; wa.K[3] = 32;
    wa.Wd[4] = g2bu_Wd; wa.ad[4] = g2bu_ad; wa.K[4] = 64;
    wa.Wd[5] = g2se_Wd; wa.ad[5] = g2se_ad; wa.K[5] = 64;
    k_wv<<<6, 64, 0, stream>>>(wa, wv);

    // ---- bias inits ----
    k_init<<<(NW * 64 + thr - 1) / thr, thr, 0, stream>>>(w1, g1ww_b, nullptr, nullptr, NW * 64);
    k_init<<<(NT * 64 + thr - 1) / thr, thr, 0, stream>>>(t1, g1bu_b, g1se_b, g1cr_b, NT * 64);
    k_init<<<(NT * 64 + thr - 1) / thr, thr, 0, stream>>>(t2, g2bu_b, g2se_b, nullptr, NT * 64);

    // ---- layer 1 ----
    // ww: wallet -> wallet
    k_src<32><<<(NW + 3) / 4, thr, 0, stream>>>(xw, g1ww_Ws, g1ww_as, hs, es, NW);
    k_agg<32><<<(NW + 3) / 4, thr, 0, stream>>>(hs, es, xw, wv + 0 * 64, offW, srtW, w1, NW);
    // bu: wallet -> token
    k_src<32><<<(NW + 3) / 4, thr, 0, stream>>>(xw, g1bu_Ws, g1bu_as, hs, es, NW);
    k_agg<32><<<(NT + 3) / 4, thr, 0, stream>>>(hs, es, xt, wv + 1 * 64, offB, srtB, t1, NT);
    // se: wallet -> token
    k_src<32><<<(NW + 3) / 4, thr, 0, stream>>>(xw, g1se_Ws, g1se_as, hs, es, NW);
    k_agg<32><<<(NT + 3) / 4, thr, 0, stream>>>(hs, es, xt, wv + 2 * 64, offS, srtS, t1, NT);
    // cr: dev -> token
    k_src<16><<<(ND + 3) / 4, thr, 0, stream>>>(xd, g1cr_Ws, g1cr_as, hs, es, ND);
    k_agg<32><<<(NT + 3) / 4, thr, 0, stream>>>(hs, es, xt, wv + 3 * 64, offC, srtC, t1, NT);

    // ---- layer 2 (w2 dead -> skipped) ----
    // bu: w1 -> t2 (dst feats = t1)
    k_src<64><<<(NW + 3) / 4, thr, 0, stream>>>(w1, g2bu_Ws, g2bu_as, hs, es, NW);
    k_agg<64><<<(NT + 3) / 4, thr, 0, stream>>>(hs, es, t1, wv + 4 * 64, offB, srtB, t2, NT);
    // se: w1 -> t2
    k_src<64><<<(NW + 3) / 4, thr, 0, stream>>>(w1, g2se_Ws, g2se_as, hs, es, NW);
    k_agg<64><<<(NT + 3) / 4, thr, 0, stream>>>(hs, es, t1, wv + 5 * 64, offS, srtS, t2, NT);

    // ---- final FC ----
    k_fc<<<(NT + 3) / 4, thr, 0, stream>>>(t2, Wfc, bfc, (float*)d_out, NT);
}

// Round 2
// 1170.586 us; speedup vs baseline: 1.3035x; 1.3035x over previous
//
#include <hip/hip_runtime.h>

#define NW 100000
#define NT 20000
#define ND 5000
#define EWW 1600000
#define EBU 1000000
#define ESE 1000000
#define ECR 20000
#define EPB 16384   // edges per block for coarse hist/scatter

// ---------------- utility kernels ----------------

__global__ void k_zero(int* __restrict__ p, int n) {
    int t = blockIdx.x * blockDim.x + threadIdx.x;
    if (t < n) p[t] = 0;
}

// init out[r*64+c] = b0[c] (+ b1[c]) (+ b2[c])
__global__ __launch_bounds__(256) void k_init(float* __restrict__ out,
                                              const float* __restrict__ b0,
                                              const float* __restrict__ b1,
                                              const float* __restrict__ b2, int n64) {
    int tid = blockIdx.x * blockDim.x + threadIdx.x;
    if (tid >= n64) return;
    int c = tid & 63;
    float v = b0[c];
    if (b1) v += b1[c];
    if (b2) v += b2[c];
    out[tid] = v;
}

// ---------------- CSR build: two-level counting sort ----------------
// A) coarse bucket histogram (LDS-aggregated)
__global__ __launch_bounds__(256) void k_chist(const int* __restrict__ dst,
                                               int* __restrict__ ccnt, int E, int shift) {
    __shared__ int sc[1024];
    for (int i = threadIdx.x; i < 1024; i += 256) sc[i] = 0;
    __syncthreads();
    int b0 = blockIdx.x * EPB;
    int end = min(b0 + EPB, E);
    for (int i = b0 + threadIdx.x; i < end; i += 256)
        atomicAdd(&sc[dst[i] >> shift], 1);
    __syncthreads();
    for (int i = threadIdx.x; i < 1024; i += 256)
        if (sc[i]) atomicAdd(&ccnt[i], sc[i]);
}

// B) coarse scan: one block per list; also writes off[Nd] = E
struct CScan {
    const int* cnt[4]; int* base[4]; int* cur[4]; int* offNd[4];
    int nbk[4]; int E[4];
};
__global__ __launch_bounds__(1024) void k_cscan(CScan a) {
    int L = blockIdx.x;
    __shared__ int sm[1024];
    int t = threadIdx.x;
    int nbk = a.nbk[L];
    int v = (t < nbk) ? a.cnt[L][t] : 0;
    sm[t] = v;
    __syncthreads();
    for (int o = 1; o < 1024; o <<= 1) {
        int u = (t >= o) ? sm[t - o] : 0;
        __syncthreads();
        sm[t] += u;
        __syncthreads();
    }
    int excl = sm[t] - v;
    if (t < nbk) { a.base[L][t] = excl; a.cur[L][t] = excl; }
    if (t == nbk) a.base[L][t] = sm[1023];   // == E (nbk < 1024 always)
    if (t == 0) a.offNd[L][0] = a.E[L];
}

// C) scatter (src,dst) pairs into coarse-bucket regions (sequential per-bucket cursors)
__global__ __launch_bounds__(256) void k_cscatter(const int* __restrict__ src,
                                                  const int* __restrict__ dst,
                                                  int2* __restrict__ pairs,
                                                  int* __restrict__ ccur, int E, int shift) {
    __shared__ int scnt[1024];
    __shared__ int sbase[1024];
    for (int i = threadIdx.x; i < 1024; i += 256) scnt[i] = 0;
    __syncthreads();
    int b0 = blockIdx.x * EPB;
    int end = min(b0 + EPB, E);
    for (int i = b0 + threadIdx.x; i < end; i += 256)
        atomicAdd(&scnt[dst[i] >> shift], 1);
    __syncthreads();
    for (int i = threadIdx.x; i < 1024; i += 256) {
        int c = scnt[i];
        sbase[i] = c ? atomicAdd(&ccur[i], c) : 0;
        scnt[i] = 0;   // reuse as local cursor (each i owned by one thread here)
    }
    __syncthreads();
    for (int i = b0 + threadIdx.x; i < end; i += 256) {
        int d = dst[i];
        int b = d >> shift;
        int p = sbase[b] + atomicAdd(&scnt[b], 1);
        pairs[p] = make_int2(src[i], d);
    }
}

// D) fine sort within one bucket per block: build final srt + off
__global__ __launch_bounds__(256) void k_fsort(const int2* __restrict__ pairs,
                                               const int* __restrict__ cbase,
                                               int* __restrict__ srt,
                                               int* __restrict__ off,
                                               int shift, int Nd) {
    int b = blockIdx.x;
    int p0 = cbase[b], p1 = cbase[b + 1];
    int width = 1 << shift;
    int mask = width - 1;
    __shared__ int fcnt[256];
    __shared__ int fbase[256];
    __shared__ int sm[256];
    int t = threadIdx.x;
    fcnt[t] = 0;
    __syncthreads();
    for (int i = p0 + t; i < p1; i += 256)
        atomicAdd(&fcnt[pairs[i].y & mask], 1);
    __syncthreads();
    int v = fcnt[t];
    sm[t] = v;
    __syncthreads();
    for (int o = 1; o < 256; o <<= 1) {
        int u = (t >= o) ? sm[t - o] : 0;
        __syncthreads();
        sm[t] += u;
        __syncthreads();
    }
    int excl = sm[t] - v;
    fbase[t] = p0 + excl;
    int d0 = b << shift;
    if (t < width && d0 + t < Nd) off[d0 + t] = p0 + excl;
    fcnt[t] = 0;   // reuse as fine cursor
    __syncthreads();
    for (int i = p0 + t; i < p1; i += 256) {
        int2 pr = pairs[i];
        int loc = pr.y & mask;
        int pos = fbase[loc] + atomicAdd(&fcnt[loc], 1);
        srt[pos] = pr.x;
    }
}

// ---------------- weight prep: wv = Wd @ a_d per relation ----------------

struct Wv6 { const float* Wd[6]; const float* ad[6]; int K[6]; };

__global__ __launch_bounds__(64) void k_wv(Wv6 a, float* __restrict__ wv) {
    int b = blockIdx.x, t = threadIdx.x;
    if (t < a.K[b]) {
        const float* Wd = a.Wd[b];
        const float* ad = a.ad[b];
        float s = 0.f;
        for (int j = 0; j < 64; ++j) s = fmaf(Wd[t * 64 + j], ad[j], s);
        wv[b * 64 + t] = s;
    }
}

// ---------------- src-side GEMM: hs = X@W [N,64], es = hs@a_s [N] ----------------

template <int K>
__global__ __launch_bounds__(256) void k_src(const float* __restrict__ X,
                                             const float* __restrict__ W,
                                             const float* __restrict__ as_,
                                             float* __restrict__ hs,
                                             float* __restrict__ es, int N) {
    int wid = (blockIdx.x * 256 + threadIdx.x) >> 6;
    int lane = threadIdx.x & 63;
    if (wid >= N) return;
    const float* xr = X + (size_t)wid * K;
    float xl = (lane < K) ? xr[lane] : 0.f;
    float acc = 0.f;
#pragma unroll
    for (int k = 0; k < K; ++k) {
        float xv = __shfl(xl, k, 64);
        acc = fmaf(xv, W[k * 64 + lane], acc);
    }
    hs[(size_t)wid * 64 + lane] = acc;
    float v = acc * as_[lane];
#pragma unroll
    for (int o = 32; o > 0; o >>= 1) v += __shfl_xor(v, o, 64);
    if (lane == 0) es[wid] = v;
}

// ---------------- pull aggregation: one wave per dst row ----------------

template <int K>
__global__ __launch_bounds__(256) void k_agg(const float* __restrict__ hs,
                                             const float* __restrict__ es,
                                             const float* __restrict__ Xd,
                                             const float* __restrict__ wv,
                                             const int* __restrict__ off,
                                             const int* __restrict__ srt,
                                             float* __restrict__ out, int Nd) {
    int wid = (blockIdx.x * 256 + threadIdx.x) >> 6;
    int lane = threadIdx.x & 63;
    if (wid >= Nd) return;
    int s0 = off[wid], s1 = off[wid + 1];
    if (s0 == s1) return;  // no incoming edges: out stays at bias init
    float p = (lane < K) ? Xd[(size_t)wid * K + lane] * wv[lane] : 0.f;
#pragma unroll
    for (int o = 32; o > 0; o >>= 1) p += __shfl_xor(p, o, 64);
    float edj = p;
    float m = -3.4e38f;
    for (int i = s0 + lane; i < s1; i += 64) {
        float ev = es[srt[i]] + edj;
        ev = ev > 0.f ? ev : 0.2f * ev;
        m = fmaxf(m, ev);
    }
#pragma unroll
    for (int o = 32; o > 0; o >>= 1) m = fmaxf(m, __shfl_xor(m, o, 64));
    float acc = 0.f, den = 0.f;
    int i = s0;
    for (; i + 1 < s1; i += 2) {
        int a0 = srt[i], a1 = srt[i + 1];
        float e0 = es[a0] + edj; e0 = e0 > 0.f ? e0 : 0.2f * e0;
        float e1 = es[a1] + edj; e1 = e1 > 0.f ? e1 : 0.2f * e1;
        float w0 = __expf(e0 - m), w1 = __expf(e1 - m);
        float h0 = hs[(size_t)a0 * 64 + lane];
        float h1 = hs[(size_t)a1 * 64 + lane];
        den += w0 + w1;
        acc = fmaf(w0, h0, acc);
        acc = fmaf(w1, h1, acc);
    }
    if (i < s1) {
        int a0 = srt[i];
        float e0 = es[a0] + edj; e0 = e0 > 0.f ? e0 : 0.2f * e0;
        float w0 = __expf(e0 - m);
        den += w0;
        acc = fmaf(w0, hs[(size_t)a0 * 64 + lane], acc);
    }
    out[(size_t)wid * 64 + lane] += acc / (den + 1e-16f);
}

// ---------------- final FC ----------------

__global__ __launch_bounds__(256) void k_fc(const float* __restrict__ t2,
                                            const float* __restrict__ Wfc,
                                            const float* __restrict__ bfc,
                                            float* __restrict__ out, int N) {
    int wid = (blockIdx.x * 256 + threadIdx.x) >> 6;
    int lane = threadIdx.x & 63;
    if (wid >= N) return;
    float v = t2[(size_t)wid * 64 + lane];
    float p0 = v * Wfc[lane * 2 + 0];
    float p1 = v * Wfc[lane * 2 + 1];
#pragma unroll
    for (int o = 32; o > 0; o >>= 1) {
        p0 += __shfl_xor(p0, o, 64);
        p1 += __shfl_xor(p1, o, 64);
    }
    if (lane == 0) {
        out[wid * 2 + 0] = p0 + bfc[0];
        out[wid * 2 + 1] = p1 + bfc[1];
    }
}

// ---------------- launcher ----------------

extern "C" void kernel_launch(void* const* d_in, const int* in_sizes, int n_in,
                              void* d_out, int out_size, void* d_ws, size_t ws_size,
                              hipStream_t stream) {
    const float* xw = (const float*)d_in[0];
    const float* xt = (const float*)d_in[1];
    const float* xd = (const float*)d_in[2];
    const float* g1ww_Ws = (const float*)d_in[3];
    const float* g1ww_Wd = (const float*)d_in[4];
    const float* g1ww_as = (const float*)d_in[5];
    const float* g1ww_ad = (const float*)d_in[6];
    const float* g1ww_b  = (const float*)d_in[7];
    const float* g1bu_Ws = (const float*)d_in[8];
    const float* g1bu_Wd = (const float*)d_in[9];
    const float* g1bu_as = (const float*)d_in[10];
    const float* g1bu_ad = (const float*)d_in[11];
    const float* g1bu_b  = (const float*)d_in[12];
    const float* g1se_Ws = (const float*)d_in[13];
    const float* g1se_Wd = (const float*)d_in[14];
    const float* g1se_as = (const float*)d_in[15];
    const float* g1se_ad = (const float*)d_in[16];
    const float* g1se_b  = (const float*)d_in[17];
    const float* g1cr_Ws = (const float*)d_in[18];
    const float* g1cr_Wd = (const float*)d_in[19];
    const float* g1cr_as = (const float*)d_in[20];
    const float* g1cr_ad = (const float*)d_in[21];
    const float* g1cr_b  = (const float*)d_in[22];
    // d_in[23..27] = g2ww params: w2 is dead code in the reference -> skipped
    const float* g2bu_Ws = (const float*)d_in[28];
    const float* g2bu_Wd = (const float*)d_in[29];
    const float* g2bu_as = (const float*)d_in[30];
    const float* g2bu_ad = (const float*)d_in[31];
    const float* g2bu_b  = (const float*)d_in[32];
    const float* g2se_Ws = (const float*)d_in[33];
    const float* g2se_Wd = (const float*)d_in[34];
    const float* g2se_as = (const float*)d_in[35];
    const float* g2se_ad = (const float*)d_in[36];
    const float* g2se_b  = (const float*)d_in[37];
    const float* Wfc = (const float*)d_in[38];
    const float* bfc = (const float*)d_in[39];
    const int* ww_src = (const int*)d_in[40];
    const int* ww_dst = (const int*)d_in[41];
    const int* bu_src = (const int*)d_in[42];
    const int* bu_dst = (const int*)d_in[43];
    const int* se_src = (const int*)d_in[44];
    const int* se_dst = (const int*)d_in[45];
    const int* cr_src = (const int*)d_in[46];
    const int* cr_dst = (const int*)d_in[47];

    const int totalE = EWW + EBU + ESE + ECR;

    // ---- workspace carve ----
    char* p = (char*)d_ws;
    auto alloc = [&](size_t bytes) {
        char* r = p;
        p += (bytes + 255) & ~(size_t)255;
        return r;
    };
    // region1: hs+es+w1, aliased by the build-phase pairs buffer (build finishes
    // before hs/es/w1 are first written; same stream => safe)
    size_t hs_b = ((size_t)NW * 64 * 4 + 255) & ~(size_t)255;
    size_t es_b = ((size_t)NW * 4 + 255) & ~(size_t)255;
    size_t w1_b = ((size_t)NW * 64 * 4 + 255) & ~(size_t)255;
    size_t pairs_b = ((size_t)totalE * 8 + 255) & ~(size_t)255;
    size_t r1_b = hs_b + es_b + w1_b;
    if (pairs_b > r1_b) r1_b = pairs_b;
    char* r1 = alloc(r1_b);
    float* hs = (float*)r1;
    float* es = (float*)(r1 + hs_b);
    float* w1 = (float*)(r1 + hs_b + es_b);
    int2* pairsW = (int2*)r1;
    int2* pairsB = pairsW + EWW;
    int2* pairsS = pairsB + EBU;
    int2* pairsC = pairsS + ESE;

    float* t1 = (float*)alloc((size_t)NT * 64 * 4);
    float* t2 = (float*)alloc((size_t)NT * 64 * 4);
    float* wv = (float*)alloc(6 * 64 * 4);
    int* ccnt  = (int*)alloc(4 * 1024 * 4);           // coarse counts, contiguous
    int* cbase = (int*)alloc(4 * 1025 * 4);           // coarse bases (+1 sentinel)
    int* ccur  = (int*)alloc(4 * 1024 * 4);           // coarse cursors
    int* offW = (int*)alloc((size_t)(NW + 1) * 4);
    int* offB = (int*)alloc((size_t)(NT + 1) * 4);
    int* offS = (int*)alloc((size_t)(NT + 1) * 4);
    int* offC = (int*)alloc((size_t)(NT + 1) * 4);
    int* srtW = (int*)alloc((size_t)EWW * 4);
    int* srtB = (int*)alloc((size_t)EBU * 4);
    int* srtS = (int*)alloc((size_t)ESE * 4);
    int* srtC = (int*)alloc((size_t)ECR * 4);

    const int thr = 256;
    // bucket config: W shift 8 (width 256, nbk 391); B/S/C shift 6 (width 64, nbk 313)
    const int SHW = 8, NBW = (NW + 255) / 256;   // 391
    const int SHT = 6, NBT = (NT + 63) / 64;     // 313

    // ---- CSR build ----
    k_zero<<<(4 * 1024 + thr - 1) / thr, thr, 0, stream>>>(ccnt, 4 * 1024);

    k_chist<<<(EWW + EPB - 1) / EPB, thr, 0, stream>>>(ww_dst, ccnt + 0 * 1024, EWW, SHW);
    k_chist<<<(EBU + EPB - 1) / EPB, thr, 0, stream>>>(bu_dst, ccnt + 1 * 1024, EBU, SHT);
    k_chist<<<(ESE + EPB - 1) / EPB, thr, 0, stream>>>(se_dst, ccnt + 2 * 1024, ESE, SHT);
    k_chist<<<(ECR + EPB - 1) / EPB, thr, 0, stream>>>(cr_dst, ccnt + 3 * 1024, ECR, SHT);

    CScan cs;
    cs.cnt[0] = ccnt + 0 * 1024; cs.base[0] = cbase + 0 * 1025; cs.cur[0] = ccur + 0 * 1024;
    cs.offNd[0] = offW + NW; cs.nbk[0] = NBW; cs.E[0] = EWW;
    cs.cnt[1] = ccnt + 1 * 1024; cs.base[1] = cbase + 1 * 1025; cs.cur[1] = ccur + 1 * 1024;
    cs.offNd[1] = offB + NT; cs.nbk[1] = NBT; cs.E[1] = EBU;
    cs.cnt[2] = ccnt + 2 * 1024; cs.base[2] = cbase + 2 * 1025; cs.cur[2] = ccur + 2 * 1024;
    cs.offNd[2] = offS + NT; cs.nbk[2] = NBT; cs.E[2] = ESE;
    cs.cnt[3] = ccnt + 3 * 1024; cs.base[3] = cbase + 3 * 1025; cs.cur[3] = ccur + 3 * 1024;
    cs.offNd[3] = offC + NT; cs.nbk[3] = NBT; cs.E[3] = ECR;
    k_cscan<<<4, 1024, 0, stream>>>(cs);

    k_cscatter<<<(EWW + EPB - 1) / EPB, thr, 0, stream>>>(ww_src, ww_dst, pairsW, ccur + 0 * 1024, EWW, SHW);
    k_cscatter<<<(EBU + EPB - 1) / EPB, thr, 0, stream>>>(bu_src, bu_dst, pairsB, ccur + 1 * 1024, EBU, SHT);
    k_cscatter<<<(ESE + EPB - 1) / EPB, thr, 0, stream>>>(se_src, se_dst, pairsS, ccur + 2 * 1024, ESE, SHT);
    k_cscatter<<<(ECR + EPB - 1) / EPB, thr, 0, stream>>>(cr_src, cr_dst, pairsC, ccur + 3 * 1024, ECR, SHT);

    k_fsort<<<NBW, thr, 0, stream>>>(pairsW, cbase + 0 * 1025, srtW, offW, SHW, NW);
    k_fsort<<<NBT, thr, 0, stream>>>(pairsB, cbase + 1 * 1025, srtB, offB, SHT, NT);
    k_fsort<<<NBT, thr, 0, stream>>>(pairsS, cbase + 2 * 1025, srtS, offS, SHT, NT);
    k_fsort<<<NBT, thr, 0, stream>>>(pairsC, cbase + 3 * 1025, srtC, offC, SHT, NT);

    // ---- wv = Wd @ a_d for the 6 live relations ----
    Wv6 wa;
    wa.Wd[0] = g1ww_Wd; wa.ad[0] = g1ww_ad; wa.K[0] = 32;
    wa.Wd[1] = g1bu_Wd; wa.ad[1] = g1bu_ad; wa.K[1] = 32;
    wa.Wd[2] = g1se_Wd; wa.ad[2] = g1se_ad; wa.K[2] = 32;
    wa.Wd[3] = g1cr_Wd; wa.ad[3] = g1cr_ad; wa.K[3] = 32;
    wa.Wd[4] = g2bu_Wd; wa.ad[4] = g2bu_ad; wa.K[4] = 64;
    wa.Wd[5] = g2se_Wd; wa.ad[5] = g2se_ad; wa.K[5] = 64;
    k_wv<<<6, 64, 0, stream>>>(wa, wv);

    // ---- bias inits (after build: w1 aliases the pairs buffer) ----
    k_init<<<(NW * 64 + thr - 1) / thr, thr, 0, stream>>>(w1, g1ww_b, nullptr, nullptr, NW * 64);
    k_init<<<(NT * 64 + thr - 1) / thr, thr, 0, stream>>>(t1, g1bu_b, g1se_b, g1cr_b, NT * 64);
    k_init<<<(NT * 64 + thr - 1) / thr, thr, 0, stream>>>(t2, g2bu_b, g2se_b, nullptr, NT * 64);

    // ---- layer 1 ----
    k_src<32><<<(NW + 3) / 4, thr, 0, stream>>>(xw, g1ww_Ws, g1ww_as, hs, es, NW);
    k_agg<32><<<(NW + 3) / 4, thr, 0, stream>>>(hs, es, xw, wv + 0 * 64, offW, srtW, w1, NW);
    k_src<32><<<(NW + 3) / 4, thr, 0, stream>>>(xw, g1bu_Ws, g1bu_as, hs, es, NW);
    k_agg<32><<<(NT + 3) / 4, thr, 0, stream>>>(hs, es, xt, wv + 1 * 64, offB, srtB, t1, NT);
    k_src<32><<<(NW + 3) / 4, thr, 0, stream>>>(xw, g1se_Ws, g1se_as, hs, es, NW);
    k_agg<32><<<(NT + 3) / 4, thr, 0, stream>>>(hs, es, xt, wv + 2 * 64, offS, srtS, t1, NT);
    k_src<16><<<(ND + 3) / 4, thr, 0, stream>>>(xd, g1cr_Ws, g1cr_as, hs, es, ND);
    k_agg<32><<<(NT + 3) / 4, thr, 0, stream>>>(hs, es, xt, wv + 3 * 64, offC, srtC, t1, NT);

    // ---- layer 2 (w2 dead -> skipped) ----
    k_src<64><<<(NW + 3) / 4, thr, 0, stream>>>(w1, g2bu_Ws, g2bu_as, hs, es, NW);
    k_agg<64><<<(NT + 3) / 4, thr, 0, stream>>>(hs, es, t1, wv + 4 * 64, offB, srtB, t2, NT);
    k_src<64><<<(NW + 3) / 4, thr, 0, stream>>>(w1, g2se_Ws, g2se_as, hs, es, NW);
    k_agg<64><<<(NT + 3) / 4, thr, 0, stream>>>(hs, es, t1, wv + 5 * 64, offS, srtS, t2, NT);

    // ---- final FC ----
    k_fc<<<(NT + 3) / 4, thr, 0, stream>>>(t2, Wfc, bfc, (float*)d_out, NT);
}

// Round 3
// 1142.974 us; speedup vs baseline: 1.3350x; 1.0242x over previous
//
#include <hip/hip_runtime.h>

#define NW 100000
#define NT 20000
#define ND 5000
#define EWW 1600000
#define EBU 1000000
#define ESE 1000000
#define ECR 20000
#define EPB 16384   // edges per block for coarse hist/scatter

typedef unsigned int uint;
typedef unsigned short ushort;

__device__ __forceinline__ float bf_lo(uint v) { return __builtin_bit_cast(float, v << 16); }
__device__ __forceinline__ float bf_hi(uint v) { return __builtin_bit_cast(float, v & 0xffff0000u); }
__device__ __forceinline__ ushort f2bf(float x) {
    uint b = __builtin_bit_cast(uint, x);
    return (ushort)((b + 0x7fffu + ((b >> 16) & 1u)) >> 16);  // RNE
}

// ---------------- utility kernels ----------------

__global__ void k_zero(int* __restrict__ p, int n) {
    int t = blockIdx.x * blockDim.x + threadIdx.x;
    if (t < n) p[t] = 0;
}

__global__ __launch_bounds__(256) void k_init(float* __restrict__ out,
                                              const float* __restrict__ b0,
                                              const float* __restrict__ b1,
                                              const float* __restrict__ b2, int n64) {
    int tid = blockIdx.x * blockDim.x + threadIdx.x;
    if (tid >= n64) return;
    int c = tid & 63;
    float v = b0[c];
    if (b1) v += b1[c];
    if (b2) v += b2[c];
    out[tid] = v;
}

// ---------------- CSR build: two-level counting sort ----------------

__global__ __launch_bounds__(256) void k_chist(const int* __restrict__ dst,
                                               int* __restrict__ ccnt, int E, int shift) {
    __shared__ int sc[1024];
    for (int i = threadIdx.x; i < 1024; i += 256) sc[i] = 0;
    __syncthreads();
    int b0 = blockIdx.x * EPB;
    int end = min(b0 + EPB, E);
    for (int i = b0 + threadIdx.x; i < end; i += 256)
        atomicAdd(&sc[dst[i] >> shift], 1);
    __syncthreads();
    for (int i = threadIdx.x; i < 1024; i += 256)
        if (sc[i]) atomicAdd(&ccnt[i], sc[i]);
}

struct CScan {
    const int* cnt[4]; int* base[4]; int* cur[4]; int* offNd[4];
    int nbk[4]; int E[4];
};
__global__ __launch_bounds__(1024) void k_cscan(CScan a) {
    int L = blockIdx.x;
    __shared__ int sm[1024];
    int t = threadIdx.x;
    int nbk = a.nbk[L];
    int v = (t < nbk) ? a.cnt[L][t] : 0;
    sm[t] = v;
    __syncthreads();
    for (int o = 1; o < 1024; o <<= 1) {
        int u = (t >= o) ? sm[t - o] : 0;
        __syncthreads();
        sm[t] += u;
        __syncthreads();
    }
    int excl = sm[t] - v;
    if (t < nbk) { a.base[L][t] = excl; a.cur[L][t] = excl; }
    if (t == nbk) a.base[L][t] = sm[1023];
    if (t == 0) a.offNd[L][0] = a.E[L];
}

__global__ __launch_bounds__(256) void k_cscatter(const int* __restrict__ src,
                                                  const int* __restrict__ dst,
                                                  int2* __restrict__ pairs,
                                                  int* __restrict__ ccur, int E, int shift) {
    __shared__ int scnt[1024];
    __shared__ int sbase[1024];
    for (int i = threadIdx.x; i < 1024; i += 256) scnt[i] = 0;
    __syncthreads();
    int b0 = blockIdx.x * EPB;
    int end = min(b0 + EPB, E);
    for (int i = b0 + threadIdx.x; i < end; i += 256)
        atomicAdd(&scnt[dst[i] >> shift], 1);
    __syncthreads();
    for (int i = threadIdx.x; i < 1024; i += 256) {
        int c = scnt[i];
        sbase[i] = c ? atomicAdd(&ccur[i], c) : 0;
        scnt[i] = 0;
    }
    __syncthreads();
    for (int i = b0 + threadIdx.x; i < end; i += 256) {
        int d = dst[i];
        int b = d >> shift;
        int p = sbase[b] + atomicAdd(&scnt[b], 1);
        pairs[p] = make_int2(src[i], d);
    }
}

__global__ __launch_bounds__(256) void k_fsort(const int2* __restrict__ pairs,
                                               const int* __restrict__ cbase,
                                               int* __restrict__ srt,
                                               int* __restrict__ off,
                                               int shift, int Nd) {
    int b = blockIdx.x;
    int p0 = cbase[b], p1 = cbase[b + 1];
    int width = 1 << shift;
    int mask = width - 1;
    __shared__ int fcnt[256];
    __shared__ int fbase[256];
    __shared__ int sm[256];
    int t = threadIdx.x;
    fcnt[t] = 0;
    __syncthreads();
    for (int i = p0 + t; i < p1; i += 256)
        atomicAdd(&fcnt[pairs[i].y & mask], 1);
    __syncthreads();
    int v = fcnt[t];
    sm[t] = v;
    __syncthreads();
    for (int o = 1; o < 256; o <<= 1) {
        int u = (t >= o) ? sm[t - o] : 0;
        __syncthreads();
        sm[t] += u;
        __syncthreads();
    }
    int excl = sm[t] - v;
    fbase[t] = p0 + excl;
    int d0 = b << shift;
    if (t < width && d0 + t < Nd) off[d0 + t] = p0 + excl;
    fcnt[t] = 0;
    __syncthreads();
    for (int i = p0 + t; i < p1; i += 256) {
        int2 pr = pairs[i];
        int loc = pr.y & mask;
        int pos = fbase[loc] + atomicAdd(&fcnt[loc], 1);
        srt[pos] = pr.x;
    }
}

// ---------------- weight prep: wv = Wd @ a_d per relation ----------------

struct Wv6 { const float* Wd[6]; const float* ad[6]; int K[6]; };

__global__ __launch_bounds__(64) void k_wv(Wv6 a, float* __restrict__ wv) {
    int b = blockIdx.x, t = threadIdx.x;
    if (t < a.K[b]) {
        const float* Wd = a.Wd[b];
        const float* ad = a.ad[b];
        float s = 0.f;
        for (int j = 0; j < 64; ++j) s = fmaf(Wd[t * 64 + j], ad[j], s);
        wv[b * 64 + t] = s;
    }
}

// ---------------- src GEMM: hsb = bf16(X@W) [N,64], es = (X@W)@a_s [N] ----------------

template <int K>
__global__ __launch_bounds__(256) void k_src(const float* __restrict__ X,
                                             const float* __restrict__ W,
                                             const float* __restrict__ as_,
                                             ushort* __restrict__ hsb,
                                             float* __restrict__ es, int N) {
    int wid = (blockIdx.x * 256 + threadIdx.x) >> 6;
    int lane = threadIdx.x & 63;
    if (wid >= N) return;
    const float* xr = X + (size_t)wid * K;
    float xl = (lane < K) ? xr[lane] : 0.f;
    float acc = 0.f;
#pragma unroll
    for (int k = 0; k < K; ++k) {
        float xv = __shfl(xl, k, 64);
        acc = fmaf(xv, W[k * 64 + lane], acc);
    }
    hsb[(size_t)wid * 64 + lane] = f2bf(acc);
    float v = acc * as_[lane];
#pragma unroll
    for (int o = 32; o > 0; o >>= 1) v += __shfl_xor(v, o, 64);
    if (lane == 0) es[wid] = v;
}

// ---------------- pull aggregation: one wave per dst row, 2 edges/iter ----------------

template <int K>
__global__ __launch_bounds__(256) void k_agg(const ushort* __restrict__ hsb,
                                             const float* __restrict__ es,
                                             const float* __restrict__ Xd,
                                             const float* __restrict__ wv,
                                             const int* __restrict__ off,
                                             const int* __restrict__ srt,
                                             float* __restrict__ out, int Nd) {
    int wid = (blockIdx.x * 256 + threadIdx.x) >> 6;
    int lane = threadIdx.x & 63;
    if (wid >= Nd) return;
    int s0 = off[wid], s1 = off[wid + 1];
    int n = s1 - s0;
    if (n <= 0) return;
    // ed for this dst row (wave-uniform)
    float p = (lane < K) ? Xd[(size_t)wid * K + lane] * wv[lane] : 0.f;
#pragma unroll
    for (int o = 32; o > 0; o >>= 1) p += __shfl_xor(p, o, 64);
    float edj = p;
    // sweep 1: gather es, compute+cache leaky logits (deg<=128 in regs), wave max
    float ev0 = -3.4e38f, ev1 = -3.4e38f;
    if (lane < n) {
        float e = es[srt[s0 + lane]] + edj;
        ev0 = e > 0.f ? e : 0.2f * e;
    }
    if (lane + 64 < n) {
        float e = es[srt[s0 + 64 + lane]] + edj;
        ev1 = e > 0.f ? e : 0.2f * e;
    }
    float m = fmaxf(ev0, ev1);
    for (int i = s0 + 128 + lane; i < s1; i += 64) {   // rare: deg > 128
        float e = es[srt[i]] + edj;
        e = e > 0.f ? e : 0.2f * e;
        m = fmaxf(m, e);
    }
#pragma unroll
    for (int o = 32; o > 0; o >>= 1) m = fmaxf(m, __shfl_xor(m, o, 64));
    // sweep 2: half-wave per edge, lane covers 2 channels (bf16 pair)
    int half = lane >> 5, l32 = lane & 31;
    float accx = 0.f, accy = 0.f, den = 0.f;
    for (int i = s0; i < s1; i += 2) {
        int j = i + half;
        bool act = j < s1;
        int jj = j - s0;
        float e0 = __shfl(ev0, jj & 63, 64);
        float e1 = __shfl(ev1, jj & 63, 64);
        float ee = (jj < 64) ? e0 : e1;
        int a = srt[act ? j : s0];
        if (jj >= 128) {            // rare fallback
            float e = es[a] + edj;
            ee = e > 0.f ? e : 0.2f * e;
        }
        float w = act ? __expf(ee - m) : 0.f;
        uint hv = ((const uint*)(hsb + (size_t)a * 64))[l32];
        den += w;
        accx = fmaf(w, bf_lo(hv), accx);
        accy = fmaf(w, bf_hi(hv), accy);
    }
    accx += __shfl_xor(accx, 32, 64);
    accy += __shfl_xor(accy, 32, 64);
    den  += __shfl_xor(den, 32, 64);
    float inv = 1.f / (den + 1e-16f);
    if (half == 0) {
        float2* orow = (float2*)(out + (size_t)wid * 64);
        float2 prev = orow[l32];
        prev.x += accx * inv;
        prev.y += accy * inv;
        orow[l32] = prev;
    }
}

// ---------------- final FC ----------------

__global__ __launch_bounds__(256) void k_fc(const float* __restrict__ t2,
                                            const float* __restrict__ Wfc,
                                            const float* __restrict__ bfc,
                                            float* __restrict__ out, int N) {
    int wid = (blockIdx.x * 256 + threadIdx.x) >> 6;
    int lane = threadIdx.x & 63;
    if (wid >= N) return;
    float v = t2[(size_t)wid * 64 + lane];
    float p0 = v * Wfc[lane * 2 + 0];
    float p1 = v * Wfc[lane * 2 + 1];
#pragma unroll
    for (int o = 32; o > 0; o >>= 1) {
        p0 += __shfl_xor(p0, o, 64);
        p1 += __shfl_xor(p1, o, 64);
    }
    if (lane == 0) {
        out[wid * 2 + 0] = p0 + bfc[0];
        out[wid * 2 + 1] = p1 + bfc[1];
    }
}

// ---------------- launcher ----------------

extern "C" void kernel_launch(void* const* d_in, const int* in_sizes, int n_in,
                              void* d_out, int out_size, void* d_ws, size_t ws_size,
                              hipStream_t stream) {
    const float* xw = (const float*)d_in[0];
    const float* xt = (const float*)d_in[1];
    const float* xd = (const float*)d_in[2];
    const float* g1ww_Ws = (const float*)d_in[3];
    const float* g1ww_Wd = (const float*)d_in[4];
    const float* g1ww_as = (const float*)d_in[5];
    const float* g1ww_ad = (const float*)d_in[6];
    const float* g1ww_b  = (const float*)d_in[7];
    const float* g1bu_Ws = (const float*)d_in[8];
    const float* g1bu_Wd = (const float*)d_in[9];
    const float* g1bu_as = (const float*)d_in[10];
    const float* g1bu_ad = (const float*)d_in[11];
    const float* g1bu_b  = (const float*)d_in[12];
    const float* g1se_Ws = (const float*)d_in[13];
    const float* g1se_Wd = (const float*)d_in[14];
    const float* g1se_as = (const float*)d_in[15];
    const float* g1se_ad = (const float*)d_in[16];
    const float* g1se_b  = (const float*)d_in[17];
    const float* g1cr_Ws = (const float*)d_in[18];
    const float* g1cr_Wd = (const float*)d_in[19];
    const float* g1cr_as = (const float*)d_in[20];
    const float* g1cr_ad = (const float*)d_in[21];
    const float* g1cr_b  = (const float*)d_in[22];
    // d_in[23..27] = g2ww params: w2 dead in reference -> skipped
    const float* g2bu_Ws = (const float*)d_in[28];
    const float* g2bu_Wd = (const float*)d_in[29];
    const float* g2bu_as = (const float*)d_in[30];
    const float* g2bu_ad = (const float*)d_in[31];
    const float* g2bu_b  = (const float*)d_in[32];
    const float* g2se_Ws = (const float*)d_in[33];
    const float* g2se_Wd = (const float*)d_in[34];
    const float* g2se_as = (const float*)d_in[35];
    const float* g2se_ad = (const float*)d_in[36];
    const float* g2se_b  = (const float*)d_in[37];
    const float* Wfc = (const float*)d_in[38];
    const float* bfc = (const float*)d_in[39];
    const int* ww_src = (const int*)d_in[40];
    const int* ww_dst = (const int*)d_in[41];
    const int* bu_src = (const int*)d_in[42];
    const int* bu_dst = (const int*)d_in[43];
    const int* se_src = (const int*)d_in[44];
    const int* se_dst = (const int*)d_in[45];
    const int* cr_src = (const int*)d_in[46];
    const int* cr_dst = (const int*)d_in[47];

    const int totalE = EWW + EBU + ESE + ECR;

    // ---- workspace carve ----
    char* p = (char*)d_ws;
    auto alloc = [&](size_t bytes) {
        char* r = p;
        p += (bytes + 255) & ~(size_t)255;
        return r;
    };
    // region1: hsb+es+w1, aliased by build-phase pairs buffer (build finishes first)
    size_t hs_b = ((size_t)NW * 64 * 2 + 255) & ~(size_t)255;   // bf16
    size_t es_b = ((size_t)NW * 4 + 255) & ~(size_t)255;
    size_t w1_b = ((size_t)NW * 64 * 4 + 255) & ~(size_t)255;
    size_t pairs_b = ((size_t)totalE * 8 + 255) & ~(size_t)255;
    size_t r1_b = hs_b + es_b + w1_b;
    if (pairs_b > r1_b) r1_b = pairs_b;
    char* r1 = alloc(r1_b);
    ushort* hsb = (ushort*)r1;
    float* es = (float*)(r1 + hs_b);
    float* w1 = (float*)(r1 + hs_b + es_b);
    int2* pairsW = (int2*)r1;
    int2* pairsB = pairsW + EWW;
    int2* pairsS = pairsB + EBU;
    int2* pairsC = pairsS + ESE;

    float* t1 = (float*)alloc((size_t)NT * 64 * 4);
    float* t2 = (float*)alloc((size_t)NT * 64 * 4);
    float* wv = (float*)alloc(6 * 64 * 4);
    int* ccnt  = (int*)alloc(4 * 1024 * 4);
    int* cbase = (int*)alloc(4 * 1025 * 4);
    int* ccur  = (int*)alloc(4 * 1024 * 4);
    int* offW = (int*)alloc((size_t)(NW + 1) * 4);
    int* offB = (int*)alloc((size_t)(NT + 1) * 4);
    int* offS = (int*)alloc((size_t)(NT + 1) * 4);
    int* offC = (int*)alloc((size_t)(NT + 1) * 4);
    int* srtW = (int*)alloc((size_t)EWW * 4);
    int* srtB = (int*)alloc((size_t)EBU * 4);
    int* srtS = (int*)alloc((size_t)ESE * 4);
    int* srtC = (int*)alloc((size_t)ECR * 4);

    const int thr = 256;
    const int SHW = 8, NBW = (NW + 255) / 256;   // 391 buckets of 256
    const int SHT = 6, NBT = (NT + 63) / 64;     // 313 buckets of 64

    // ---- CSR build ----
    k_zero<<<(4 * 1024 + thr - 1) / thr, thr, 0, stream>>>(ccnt, 4 * 1024);

    k_chist<<<(EWW + EPB - 1) / EPB, thr, 0, stream>>>(ww_dst, ccnt + 0 * 1024, EWW, SHW);
    k_chist<<<(EBU + EPB - 1) / EPB, thr, 0, stream>>>(bu_dst, ccnt + 1 * 1024, EBU, SHT);
    k_chist<<<(ESE + EPB - 1) / EPB, thr, 0, stream>>>(se_dst, ccnt + 2 * 1024, ESE, SHT);
    k_chist<<<(ECR + EPB - 1) / EPB, thr, 0, stream>>>(cr_dst, ccnt + 3 * 1024, ECR, SHT);

    CScan cs;
    cs.cnt[0] = ccnt + 0 * 1024; cs.base[0] = cbase + 0 * 1025; cs.cur[0] = ccur + 0 * 1024;
    cs.offNd[0] = offW + NW; cs.nbk[0] = NBW; cs.E[0] = EWW;
    cs.cnt[1] = ccnt + 1 * 1024; cs.base[1] = cbase + 1 * 1025; cs.cur[1] = ccur + 1 * 1024;
    cs.offNd[1] = offB + NT; cs.nbk[1] = NBT; cs.E[1] = EBU;
    cs.cnt[2] = ccnt + 2 * 1024; cs.base[2] = cbase + 2 * 1025; cs.cur[2] = ccur + 2 * 1024;
    cs.offNd[2] = offS + NT; cs.nbk[2] = NBT; cs.E[2] = ESE;
    cs.cnt[3] = ccnt + 3 * 1024; cs.base[3] = cbase + 3 * 1025; cs.cur[3] = ccur + 3 * 1024;
    cs.offNd[3] = offC + NT; cs.nbk[3] = NBT; cs.E[3] = ECR;
    k_cscan<<<4, 1024, 0, stream>>>(cs);

    k_cscatter<<<(EWW + EPB - 1) / EPB, thr, 0, stream>>>(ww_src, ww_dst, pairsW, ccur + 0 * 1024, EWW, SHW);
    k_cscatter<<<(EBU + EPB - 1) / EPB, thr, 0, stream>>>(bu_src, bu_dst, pairsB, ccur + 1 * 1024, EBU, SHT);
    k_cscatter<<<(ESE + EPB - 1) / EPB, thr, 0, stream>>>(se_src, se_dst, pairsS, ccur + 2 * 1024, ESE, SHT);
    k_cscatter<<<(ECR + EPB - 1) / EPB, thr, 0, stream>>>(cr_src, cr_dst, pairsC, ccur + 3 * 1024, ECR, SHT);

    k_fsort<<<NBW, thr, 0, stream>>>(pairsW, cbase + 0 * 1025, srtW, offW, SHW, NW);
    k_fsort<<<NBT, thr, 0, stream>>>(pairsB, cbase + 1 * 1025, srtB, offB, SHT, NT);
    k_fsort<<<NBT, thr, 0, stream>>>(pairsS, cbase + 2 * 1025, srtS, offS, SHT, NT);
    k_fsort<<<NBT, thr, 0, stream>>>(pairsC, cbase + 3 * 1025, srtC, offC, SHT, NT);

    // ---- wv = Wd @ a_d ----
    Wv6 wa;
    wa.Wd[0] = g1ww_Wd; wa.ad[0] = g1ww_ad; wa.K[0] = 32;
    wa.Wd[1] = g1bu_Wd; wa.ad[1] = g1bu_ad; wa.K[1] = 32;
    wa.Wd[2] = g1se_Wd; wa.ad[2] = g1se_ad; wa.K[2] = 32;
    wa.Wd[3] = g1cr_Wd; wa.ad[3] = g1cr_ad; wa.K[3] = 32;
    wa.Wd[4] = g2bu_Wd; wa.ad[4] = g2bu_ad; wa.K[4] = 64;
    wa.Wd[5] = g2se_Wd; wa.ad[5] = g2se_ad; wa.K[5] = 64;
    k_wv<<<6, 64, 0, stream>>>(wa, wv);

    // ---- bias inits (after build: w1 aliases pairs buffer) ----
    k_init<<<(NW * 64 + thr - 1) / thr, thr, 0, stream>>>(w1, g1ww_b, nullptr, nullptr, NW * 64);
    k_init<<<(NT * 64 + thr - 1) / thr, thr, 0, stream>>>(t1, g1bu_b, g1se_b, g1cr_b, NT * 64);
    k_init<<<(NT * 64 + thr - 1) / thr, thr, 0, stream>>>(t2, g2bu_b, g2se_b, nullptr, NT * 64);

    // ---- layer 1 ----
    k_src<32><<<(NW + 3) / 4, thr, 0, stream>>>(xw, g1ww_Ws, g1ww_as, hsb, es, NW);
    k_agg<32><<<(NW + 3) / 4, thr, 0, stream>>>(hsb, es, xw, wv + 0 * 64, offW, srtW, w1, NW);
    k_src<32><<<(NW + 3) / 4, thr, 0, stream>>>(xw, g1bu_Ws, g1bu_as, hsb, es, NW);
    k_agg<32><<<(NT + 3) / 4, thr, 0, stream>>>(hsb, es, xt, wv + 1 * 64, offB, srtB, t1, NT);
    k_src<32><<<(NW + 3) / 4, thr, 0, stream>>>(xw, g1se_Ws, g1se_as, hsb, es, NW);
    k_agg<32><<<(NT + 3) / 4, thr, 0, stream>>>(hsb, es, xt, wv + 2 * 64, offS, srtS, t1, NT);
    k_src<16><<<(ND + 3) / 4, thr, 0, stream>>>(xd, g1cr_Ws, g1cr_as, hsb, es, ND);
    k_agg<32><<<(NT + 3) / 4, thr, 0, stream>>>(hsb, es, xt, wv + 3 * 64, offC, srtC, t1, NT);

    // ---- layer 2 (w2 dead -> skipped) ----
    k_src<64><<<(NW + 3) / 4, thr, 0, stream>>>(w1, g2bu_Ws, g2bu_as, hsb, es, NW);
    k_agg<64><<<(NT + 3) / 4, thr, 0, stream>>>(hsb, es, t1, wv + 4 * 64, offB, srtB, t2, NT);
    k_src<64><<<(NW + 3) / 4, thr, 0, stream>>>(w1, g2se_Ws, g2se_as, hsb, es, NW);
    k_agg<64><<<(NT + 3) / 4, thr, 0, stream>>>(hsb, es, t1, wv + 5 * 64, offS, srtS, t2, NT);

    // ---- final FC ----
    k_fc<<<(NT + 3) / 4, thr, 0, stream>>>(t2, Wfc, bfc, (float*)d_out, NT);
}

// Round 4
// 954.305 us; speedup vs baseline: 1.5990x; 1.1977x over previous
//
#include <hip/hip_runtime.h>

#define NW 100000
#define NT 20000
#define ND 5000
#define EWW 1600000
#define EBU 1000000
#define ESE 1000000
#define ECR 20000
#define EPB 16384   // edges per block for coarse hist/scatter

typedef unsigned int uint;
typedef unsigned short ushort;

__device__ __forceinline__ float bf_lo(uint v) { return __builtin_bit_cast(float, v << 16); }
__device__ __forceinline__ float bf_hi(uint v) { return __builtin_bit_cast(float, v & 0xffff0000u); }
__device__ __forceinline__ ushort f2bf(float x) {
    uint b = __builtin_bit_cast(uint, x);
    return (ushort)((b + 0x7fffu + ((b >> 16) & 1u)) >> 16);  // RNE
}

// ---------------- utility kernels ----------------

__global__ void k_zero(int* __restrict__ p, int n) {
    int t = blockIdx.x * blockDim.x + threadIdx.x;
    if (t < n) p[t] = 0;
}

// bias-sum helper: out[c] = b0[c] + b1[c] (+ b2[c])
__global__ __launch_bounds__(64) void k_bsum(const float* __restrict__ b0,
                                             const float* __restrict__ b1,
                                             const float* __restrict__ b2,
                                             float* __restrict__ out) {
    int t = threadIdx.x;
    float v = b0[t] + b1[t];
    if (b2) v += b2[t];
    out[t] = v;
}

// ---------------- CSR build: two-level counting sort ----------------

__global__ __launch_bounds__(256) void k_chist(const int* __restrict__ dst,
                                               int* __restrict__ ccnt, int E, int shift) {
    __shared__ int sc[1024];
    for (int i = threadIdx.x; i < 1024; i += 256) sc[i] = 0;
    __syncthreads();
    int b0 = blockIdx.x * EPB;
    int end = min(b0 + EPB, E);
    for (int i = b0 + threadIdx.x; i < end; i += 256)
        atomicAdd(&sc[dst[i] >> shift], 1);
    __syncthreads();
    for (int i = threadIdx.x; i < 1024; i += 256)
        if (sc[i]) atomicAdd(&ccnt[i], sc[i]);
}

struct CScan {
    const int* cnt[4]; int* base[4]; int* cur[4]; int* offNd[4];
    int nbk[4]; int E[4];
};
__global__ __launch_bounds__(1024) void k_cscan(CScan a) {
    int L = blockIdx.x;
    __shared__ int sm[1024];
    int t = threadIdx.x;
    int nbk = a.nbk[L];
    int v = (t < nbk) ? a.cnt[L][t] : 0;
    sm[t] = v;
    __syncthreads();
    for (int o = 1; o < 1024; o <<= 1) {
        int u = (t >= o) ? sm[t - o] : 0;
        __syncthreads();
        sm[t] += u;
        __syncthreads();
    }
    int excl = sm[t] - v;
    if (t < nbk) { a.base[L][t] = excl; a.cur[L][t] = excl; }
    if (t == nbk) a.base[L][t] = sm[1023];
    if (t == 0) a.offNd[L][0] = a.E[L];
}

__global__ __launch_bounds__(256) void k_cscatter(const int* __restrict__ src,
                                                  const int* __restrict__ dst,
                                                  int2* __restrict__ pairs,
                                                  int* __restrict__ ccur, int E, int shift) {
    __shared__ int scnt[1024];
    __shared__ int sbase[1024];
    for (int i = threadIdx.x; i < 1024; i += 256) scnt[i] = 0;
    __syncthreads();
    int b0 = blockIdx.x * EPB;
    int end = min(b0 + EPB, E);
    for (int i = b0 + threadIdx.x; i < end; i += 256)
        atomicAdd(&scnt[dst[i] >> shift], 1);
    __syncthreads();
    for (int i = threadIdx.x; i < 1024; i += 256) {
        int c = scnt[i];
        sbase[i] = c ? atomicAdd(&ccur[i], c) : 0;
        scnt[i] = 0;
    }
    __syncthreads();
    for (int i = b0 + threadIdx.x; i < end; i += 256) {
        int d = dst[i];
        int b = d >> shift;
        int p = sbase[b] + atomicAdd(&scnt[b], 1);
        pairs[p] = make_int2(src[i], d);
    }
}

__global__ __launch_bounds__(256) void k_fsort(const int2* __restrict__ pairs,
                                               const int* __restrict__ cbase,
                                               int* __restrict__ srt,
                                               int* __restrict__ off,
                                               int shift, int Nd) {
    int b = blockIdx.x;
    int p0 = cbase[b], p1 = cbase[b + 1];
    int width = 1 << shift;
    int mask = width - 1;
    __shared__ int fcnt[256];
    __shared__ int fbase[256];
    __shared__ int sm[256];
    int t = threadIdx.x;
    fcnt[t] = 0;
    __syncthreads();
    for (int i = p0 + t; i < p1; i += 256)
        atomicAdd(&fcnt[pairs[i].y & mask], 1);
    __syncthreads();
    int v = fcnt[t];
    sm[t] = v;
    __syncthreads();
    for (int o = 1; o < 256; o <<= 1) {
        int u = (t >= o) ? sm[t - o] : 0;
        __syncthreads();
        sm[t] += u;
        __syncthreads();
    }
    int excl = sm[t] - v;
    fbase[t] = p0 + excl;
    int d0 = b << shift;
    if (t < width && d0 + t < Nd) off[d0 + t] = p0 + excl;
    fcnt[t] = 0;
    __syncthreads();
    for (int i = p0 + t; i < p1; i += 256) {
        int2 pr = pairs[i];
        int loc = pr.y & mask;
        int pos = fbase[loc] + atomicAdd(&fcnt[loc], 1);
        srt[pos] = pr.x;
    }
}

// ---------------- weight prep: wv = Wd @ a_d per relation ----------------

struct Wv6 { const float* Wd[6]; const float* ad[6]; int K[6]; };

__global__ __launch_bounds__(64) void k_wv(Wv6 a, float* __restrict__ wv) {
    int b = blockIdx.x, t = threadIdx.x;
    if (t < a.K[b]) {
        const float* Wd = a.Wd[b];
        const float* ad = a.ad[b];
        float s = 0.f;
        for (int j = 0; j < 64; ++j) s = fmaf(Wd[t * 64 + j], ad[j], s);
        wv[b * 64 + t] = s;
    }
}

// ---------------- src GEMM: hsb = bf16(X@W) [N,64], es = (X@W)@a_s [N] ----------------

template <int K>
__global__ __launch_bounds__(256) void k_src(const float* __restrict__ X,
                                             const float* __restrict__ W,
                                             const float* __restrict__ as_,
                                             ushort* __restrict__ hsb,
                                             float* __restrict__ es, int N) {
    int wid = (blockIdx.x * 256 + threadIdx.x) >> 6;
    int lane = threadIdx.x & 63;
    if (wid >= N) return;
    const float* xr = X + (size_t)wid * K;
    float xl = (lane < K) ? xr[lane] : 0.f;
    float acc = 0.f;
#pragma unroll
    for (int k = 0; k < K; ++k) {
        float xv = __shfl(xl, k, 64);
        acc = fmaf(xv, W[k * 64 + lane], acc);
    }
    hsb[(size_t)wid * 64 + lane] = f2bf(acc);
    float v = acc * as_[lane];
#pragma unroll
    for (int o = 32; o > 0; o >>= 1) v += __shfl_xor(v, o, 64);
    if (lane == 0) es[wid] = v;
}

// ---------------- pull aggregation: one wave per dst row ----------------
// 16-lane group per edge (uint2 row load), 8 edges in flight, indices cached
// from sweep 1 (no dependent srt reload). ACCUM: out += contrib (row untouched
// if no edges). !ACCUM: out = bias + contrib (bias row written even if 0 edges).

template <int K, bool ACCUM>
__global__ __launch_bounds__(256) void k_agg(const ushort* __restrict__ hsb,
                                             const float* __restrict__ es,
                                             const float* __restrict__ Xd,
                                             const float* __restrict__ wv,
                                             const float* __restrict__ bias,
                                             const int* __restrict__ off,
                                             const int* __restrict__ srt,
                                             float* __restrict__ out, int Nd) {
    int wid = (blockIdx.x * 256 + threadIdx.x) >> 6;
    int lane = threadIdx.x & 63;
    if (wid >= Nd) return;
    int s0 = off[wid], s1 = off[wid + 1];
    int n = s1 - s0;
    if (n <= 0) {
        if (!ACCUM) out[(size_t)wid * 64 + lane] = bias[lane];
        return;
    }
    // ed for this dst row (wave-uniform)
    float p = (lane < K) ? Xd[(size_t)wid * K + lane] * wv[lane] : 0.f;
#pragma unroll
    for (int o = 32; o > 0; o >>= 1) p += __shfl_xor(p, o, 64);
    float edj = p;
    // sweep 1: gather es + cache indices & leaky logits (deg<=128 in regs), wave max
    int aidx0 = 0, aidx1 = 0;
    float ev0 = -3.4e38f, ev1 = -3.4e38f;
    if (lane < n) {
        aidx0 = srt[s0 + lane];
        float e = es[aidx0] + edj;
        ev0 = e > 0.f ? e : 0.2f * e;
    }
    if (lane + 64 < n) {
        aidx1 = srt[s0 + 64 + lane];
        float e = es[aidx1] + edj;
        ev1 = e > 0.f ? e : 0.2f * e;
    }
    float m = fmaxf(ev0, ev1);
    for (int i = s0 + 128 + lane; i < s1; i += 64) {   // rare: deg > 128
        float e = es[srt[i]] + edj;
        e = e > 0.f ? e : 0.2f * e;
        m = fmaxf(m, e);
    }
#pragma unroll
    for (int o = 32; o > 0; o >>= 1) m = fmaxf(m, __shfl_xor(m, o, 64));
    // sweep 2: 16-lane group per edge, lane covers 4 bf16 channels, 8 edges/iter
    int g = lane >> 4, l16 = lane & 15;
    float a0 = 0.f, a1 = 0.f, a2 = 0.f, a3 = 0.f, den = 0.f;
    for (int i = s0; i < s1; i += 8) {
#pragma unroll
        for (int u = 0; u < 2; ++u) {
            int j = i + u * 4 + g;
            bool act = j < s1;
            int jj = j - s0;
            int idx = jj & 63;
            float eA = __shfl(ev0, idx, 64);
            float eB = __shfl(ev1, idx, 64);
            int iA = __shfl(aidx0, idx, 64);
            int iB = __shfl(aidx1, idx, 64);
            float ee = (jj < 64) ? eA : eB;
            int a = (jj < 64) ? iA : iB;
            if (jj >= 128) {       // rare fallback
                a = srt[act ? j : s0];
                float e = es[a] + edj;
                ee = e > 0.f ? e : 0.2f * e;
            }
            float w = act ? __expf(ee - m) : 0.f;
            uint2 hv = ((const uint2*)(hsb + (size_t)a * 64))[l16];
            den += w;
            a0 = fmaf(w, bf_lo(hv.x), a0);
            a1 = fmaf(w, bf_hi(hv.x), a1);
            a2 = fmaf(w, bf_lo(hv.y), a2);
            a3 = fmaf(w, bf_hi(hv.y), a3);
        }
    }
#pragma unroll
    for (int o = 16; o <= 32; o <<= 1) {
        a0 += __shfl_xor(a0, o, 64);
        a1 += __shfl_xor(a1, o, 64);
        a2 += __shfl_xor(a2, o, 64);
        a3 += __shfl_xor(a3, o, 64);
        den += __shfl_xor(den, o, 64);
    }
    float inv = 1.f / (den + 1e-16f);
    if (g == 0) {
        float4* orow = (float4*)(out + (size_t)wid * 64);
        float4 r;
        if (ACCUM) {
            float4 prev = orow[l16];
            r.x = prev.x + a0 * inv;
            r.y = prev.y + a1 * inv;
            r.z = prev.z + a2 * inv;
            r.w = prev.w + a3 * inv;
        } else {
            r.x = bias[l16 * 4 + 0] + a0 * inv;
            r.y = bias[l16 * 4 + 1] + a1 * inv;
            r.z = bias[l16 * 4 + 2] + a2 * inv;
            r.w = bias[l16 * 4 + 3] + a3 * inv;
        }
        orow[l16] = r;
    }
}

// ---------------- final FC ----------------

__global__ __launch_bounds__(256) void k_fc(const float* __restrict__ t2,
                                            const float* __restrict__ Wfc,
                                            const float* __restrict__ bfc,
                                            float* __restrict__ out, int N) {
    int wid = (blockIdx.x * 256 + threadIdx.x) >> 6;
    int lane = threadIdx.x & 63;
    if (wid >= N) return;
    float v = t2[(size_t)wid * 64 + lane];
    float p0 = v * Wfc[lane * 2 + 0];
    float p1 = v * Wfc[lane * 2 + 1];
#pragma unroll
    for (int o = 32; o > 0; o >>= 1) {
        p0 += __shfl_xor(p0, o, 64);
        p1 += __shfl_xor(p1, o, 64);
    }
    if (lane == 0) {
        out[wid * 2 + 0] = p0 + bfc[0];
        out[wid * 2 + 1] = p1 + bfc[1];
    }
}

// ---------------- launcher ----------------

extern "C" void kernel_launch(void* const* d_in, const int* in_sizes, int n_in,
                              void* d_out, int out_size, void* d_ws, size_t ws_size,
                              hipStream_t stream) {
    const float* xw = (const float*)d_in[0];
    const float* xt = (const float*)d_in[1];
    const float* xd = (const float*)d_in[2];
    const float* g1ww_Ws = (const float*)d_in[3];
    const float* g1ww_Wd = (const float*)d_in[4];
    const float* g1ww_as = (const float*)d_in[5];
    const float* g1ww_ad = (const float*)d_in[6];
    const float* g1ww_b  = (const float*)d_in[7];
    const float* g1bu_Ws = (const float*)d_in[8];
    const float* g1bu_Wd = (const float*)d_in[9];
    const float* g1bu_as = (const float*)d_in[10];
    const float* g1bu_ad = (const float*)d_in[11];
    const float* g1bu_b  = (const float*)d_in[12];
    const float* g1se_Ws = (const float*)d_in[13];
    const float* g1se_Wd = (const float*)d_in[14];
    const float* g1se_as = (const float*)d_in[15];
    const float* g1se_ad = (const float*)d_in[16];
    const float* g1se_b  = (const float*)d_in[17];
    const float* g1cr_Ws = (const float*)d_in[18];
    const float* g1cr_Wd = (const float*)d_in[19];
    const float* g1cr_as = (const float*)d_in[20];
    const float* g1cr_ad = (const float*)d_in[21];
    const float* g1cr_b  = (const float*)d_in[22];
    // d_in[23..27] = g2ww params: w2 dead in reference -> skipped
    const float* g2bu_Ws = (const float*)d_in[28];
    const float* g2bu_Wd = (const float*)d_in[29];
    const float* g2bu_as = (const float*)d_in[30];
    const float* g2bu_ad = (const float*)d_in[31];
    const float* g2bu_b  = (const float*)d_in[32];
    const float* g2se_Ws = (const float*)d_in[33];
    const float* g2se_Wd = (const float*)d_in[34];
    const float* g2se_as = (const float*)d_in[35];
    const float* g2se_ad = (const float*)d_in[36];
    const float* g2se_b  = (const float*)d_in[37];
    const float* Wfc = (const float*)d_in[38];
    const float* bfc = (const float*)d_in[39];
    const int* ww_src = (const int*)d_in[40];
    const int* ww_dst = (const int*)d_in[41];
    const int* bu_src = (const int*)d_in[42];
    const int* bu_dst = (const int*)d_in[43];
    const int* se_src = (const int*)d_in[44];
    const int* se_dst = (const int*)d_in[45];
    const int* cr_src = (const int*)d_in[46];
    const int* cr_dst = (const int*)d_in[47];

    const int totalE = EWW + EBU + ESE + ECR;

    // ---- workspace carve ----
    char* p = (char*)d_ws;
    auto alloc = [&](size_t bytes) {
        char* r = p;
        p += (bytes + 255) & ~(size_t)255;
        return r;
    };
    // region1: hsb+es+w1, aliased by build-phase pairs buffer (build finishes first)
    size_t hs_b = ((size_t)NW * 64 * 2 + 255) & ~(size_t)255;   // bf16
    size_t es_b = ((size_t)NW * 4 + 255) & ~(size_t)255;
    size_t w1_b = ((size_t)NW * 64 * 4 + 255) & ~(size_t)255;
    size_t pairs_b = ((size_t)totalE * 8 + 255) & ~(size_t)255;
    size_t r1_b = hs_b + es_b + w1_b;
    if (pairs_b > r1_b) r1_b = pairs_b;
    char* r1 = alloc(r1_b);
    ushort* hsb = (ushort*)r1;
    float* es = (float*)(r1 + hs_b);
    float* w1 = (float*)(r1 + hs_b + es_b);
    int2* pairsW = (int2*)r1;
    int2* pairsB = pairsW + EWW;
    int2* pairsS = pairsB + EBU;
    int2* pairsC = pairsS + ESE;

    float* t1 = (float*)alloc((size_t)NT * 64 * 4);
    float* t2 = (float*)alloc((size_t)NT * 64 * 4);
    float* wv = (float*)alloc(6 * 64 * 4);
    float* biasT1 = (float*)alloc(64 * 4);
    float* biasT2 = (float*)alloc(64 * 4);
    int* ccnt  = (int*)alloc(4 * 1024 * 4);
    int* cbase = (int*)alloc(4 * 1025 * 4);
    int* ccur  = (int*)alloc(4 * 1024 * 4);
    int* offW = (int*)alloc((size_t)(NW + 1) * 4);
    int* offB = (int*)alloc((size_t)(NT + 1) * 4);
    int* offS = (int*)alloc((size_t)(NT + 1) * 4);
    int* offC = (int*)alloc((size_t)(NT + 1) * 4);
    int* srtW = (int*)alloc((size_t)EWW * 4);
    int* srtB = (int*)alloc((size_t)EBU * 4);
    int* srtS = (int*)alloc((size_t)ESE * 4);
    int* srtC = (int*)alloc((size_t)ECR * 4);

    const int thr = 256;
    const int SHW = 8, NBW = (NW + 255) / 256;   // 391 buckets of 256
    const int SHT = 6, NBT = (NT + 63) / 64;     // 313 buckets of 64

    // ---- CSR build ----
    k_zero<<<(4 * 1024 + thr - 1) / thr, thr, 0, stream>>>(ccnt, 4 * 1024);

    k_chist<<<(EWW + EPB - 1) / EPB, thr, 0, stream>>>(ww_dst, ccnt + 0 * 1024, EWW, SHW);
    k_chist<<<(EBU + EPB - 1) / EPB, thr, 0, stream>>>(bu_dst, ccnt + 1 * 1024, EBU, SHT);
    k_chist<<<(ESE + EPB - 1) / EPB, thr, 0, stream>>>(se_dst, ccnt + 2 * 1024, ESE, SHT);
    k_chist<<<(ECR + EPB - 1) / EPB, thr, 0, stream>>>(cr_dst, ccnt + 3 * 1024, ECR, SHT);

    CScan cs;
    cs.cnt[0] = ccnt + 0 * 1024; cs.base[0] = cbase + 0 * 1025; cs.cur[0] = ccur + 0 * 1024;
    cs.offNd[0] = offW + NW; cs.nbk[0] = NBW; cs.E[0] = EWW;
    cs.cnt[1] = ccnt + 1 * 1024; cs.base[1] = cbase + 1 * 1025; cs.cur[1] = ccur + 1 * 1024;
    cs.offNd[1] = offB + NT; cs.nbk[1] = NBT; cs.E[1] = EBU;
    cs.cnt[2] = ccnt + 2 * 1024; cs.base[2] = cbase + 2 * 1025; cs.cur[2] = ccur + 2 * 1024;
    cs.offNd[2] = offS + NT; cs.nbk[2] = NBT; cs.E[2] = ESE;
    cs.cnt[3] = ccnt + 3 * 1024; cs.base[3] = cbase + 3 * 1025; cs.cur[3] = ccur + 3 * 1024;
    cs.offNd[3] = offC + NT; cs.nbk[3] = NBT; cs.E[3] = ECR;
    k_cscan<<<4, 1024, 0, stream>>>(cs);

    k_cscatter<<<(EWW + EPB - 1) / EPB, thr, 0, stream>>>(ww_src, ww_dst, pairsW, ccur + 0 * 1024, EWW, SHW);
    k_cscatter<<<(EBU + EPB - 1) / EPB, thr, 0, stream>>>(bu_src, bu_dst, pairsB, ccur + 1 * 1024, EBU, SHT);
    k_cscatter<<<(ESE + EPB - 1) / EPB, thr, 0, stream>>>(se_src, se_dst, pairsS, ccur + 2 * 1024, ESE, SHT);
    k_cscatter<<<(ECR + EPB - 1) / EPB, thr, 0, stream>>>(cr_src, cr_dst, pairsC, ccur + 3 * 1024, ECR, SHT);

    k_fsort<<<NBW, thr, 0, stream>>>(pairsW, cbase + 0 * 1025, srtW, offW, SHW, NW);
    k_fsort<<<NBT, thr, 0, stream>>>(pairsB, cbase + 1 * 1025, srtB, offB, SHT, NT);
    k_fsort<<<NBT, thr, 0, stream>>>(pairsS, cbase + 2 * 1025, srtS, offS, SHT, NT);
    k_fsort<<<NBT, thr, 0, stream>>>(pairsC, cbase + 3 * 1025, srtC, offC, SHT, NT);

    // ---- wv = Wd @ a_d + combined biases ----
    Wv6 wa;
    wa.Wd[0] = g1ww_Wd; wa.ad[0] = g1ww_ad; wa.K[0] = 32;
    wa.Wd[1] = g1bu_Wd; wa.ad[1] = g1bu_ad; wa.K[1] = 32;
    wa.Wd[2] = g1se_Wd; wa.ad[2] = g1se_ad; wa.K[2] = 32;
    wa.Wd[3] = g1cr_Wd; wa.ad[3] = g1cr_ad; wa.K[3] = 32;
    wa.Wd[4] = g2bu_Wd; wa.ad[4] = g2bu_ad; wa.K[4] = 64;
    wa.Wd[5] = g2se_Wd; wa.ad[5] = g2se_ad; wa.K[5] = 64;
    k_wv<<<6, 64, 0, stream>>>(wa, wv);
    k_bsum<<<1, 64, 0, stream>>>(g1bu_b, g1se_b, g1cr_b, biasT1);
    k_bsum<<<1, 64, 0, stream>>>(g2bu_b, g2se_b, nullptr, biasT2);

    // ---- layer 1 ----
    k_src<32><<<(NW + 3) / 4, thr, 0, stream>>>(xw, g1ww_Ws, g1ww_as, hsb, es, NW);
    k_agg<32, false><<<(NW + 3) / 4, thr, 0, stream>>>(hsb, es, xw, wv + 0 * 64, g1ww_b, offW, srtW, w1, NW);
    k_src<32><<<(NW + 3) / 4, thr, 0, stream>>>(xw, g1bu_Ws, g1bu_as, hsb, es, NW);
    k_agg<32, false><<<(NT + 3) / 4, thr, 0, stream>>>(hsb, es, xt, wv + 1 * 64, biasT1, offB, srtB, t1, NT);
    k_src<32><<<(NW + 3) / 4, thr, 0, stream>>>(xw, g1se_Ws, g1se_as, hsb, es, NW);
    k_agg<32, true><<<(NT + 3) / 4, thr, 0, stream>>>(hsb, es, xt, wv + 2 * 64, nullptr, offS, srtS, t1, NT);
    k_src<16><<<(ND + 3) / 4, thr, 0, stream>>>(xd, g1cr_Ws, g1cr_as, hsb, es, ND);
    k_agg<32, true><<<(NT + 3) / 4, thr, 0, stream>>>(hsb, es, xt, wv + 3 * 64, nullptr, offC, srtC, t1, NT);

    // ---- layer 2 (w2 dead -> skipped) ----
    k_src<64><<<(NW + 3) / 4, thr, 0, stream>>>(w1, g2bu_Ws, g2bu_as, hsb, es, NW);
    k_agg<64, false><<<(NT + 3) / 4, thr, 0, stream>>>(hsb, es, t1, wv + 4 * 64, biasT2, offB, srtB, t2, NT);
    k_src<64><<<(NW + 3) / 4, thr, 0, stream>>>(w1, g2se_Ws, g2se_as, hsb, es, NW);
    k_agg<64, true><<<(NT + 3) / 4, thr, 0, stream>>>(hsb, es, t1, wv + 5 * 64, nullptr, offS, srtS, t2, NT);

    // ---- final FC ----
    k_fc<<<(NT + 3) / 4, thr, 0, stream>>>(t2, Wfc, bfc, (float*)d_out, NT);
}

// Round 5
// 776.749 us; speedup vs baseline: 1.9645x; 1.2286x over previous
//
#include <hip/hip_runtime.h>

#define NW 100000
#define NT 20000
#define ND 5000
#define EWW 1600000
#define EBU 1000000
#define ESE 1000000
#define ECR 20000
#define EPB 16384   // edges per block for coarse hist/scatter

typedef unsigned int uint;
typedef unsigned short ushort;

__device__ __forceinline__ float bf_lo(uint v) { return __builtin_bit_cast(float, v << 16); }
__device__ __forceinline__ float bf_hi(uint v) { return __builtin_bit_cast(float, v & 0xffff0000u); }
__device__ __forceinline__ ushort f2bf(float x) {
    uint b = __builtin_bit_cast(uint, x);
    return (ushort)((b + 0x7fffu + ((b >> 16) & 1u)) >> 16);  // RNE
}

// ---------------- utility kernels ----------------

__global__ void k_zero(int* __restrict__ p, int n) {
    int t = blockIdx.x * blockDim.x + threadIdx.x;
    if (t < n) p[t] = 0;
}

// bias-sum helper: out[c] = b0[c] + b1[c] (+ b2[c])
__global__ __launch_bounds__(64) void k_bsum(const float* __restrict__ b0,
                                             const float* __restrict__ b1,
                                             const float* __restrict__ b2,
                                             float* __restrict__ out) {
    int t = threadIdx.x;
    float v = b0[t] + b1[t];
    if (b2) v += b2[t];
    out[t] = v;
}

// ---------------- CSR build: two-level counting sort ----------------

__global__ __launch_bounds__(256) void k_chist(const int* __restrict__ dst,
                                               int* __restrict__ ccnt, int E, int shift) {
    __shared__ int sc[1024];
    for (int i = threadIdx.x; i < 1024; i += 256) sc[i] = 0;
    __syncthreads();
    int b0 = blockIdx.x * EPB;
    int end = min(b0 + EPB, E);
    for (int i = b0 + threadIdx.x; i < end; i += 256)
        atomicAdd(&sc[dst[i] >> shift], 1);
    __syncthreads();
    for (int i = threadIdx.x; i < 1024; i += 256)
        if (sc[i]) atomicAdd(&ccnt[i], sc[i]);
}

struct CScan {
    const int* cnt[4]; int* base[4]; int* cur[4]; int* offNd[4];
    int nbk[4]; int E[4];
};
__global__ __launch_bounds__(1024) void k_cscan(CScan a) {
    int L = blockIdx.x;
    __shared__ int sm[1024];
    int t = threadIdx.x;
    int nbk = a.nbk[L];
    int v = (t < nbk) ? a.cnt[L][t] : 0;
    sm[t] = v;
    __syncthreads();
    for (int o = 1; o < 1024; o <<= 1) {
        int u = (t >= o) ? sm[t - o] : 0;
        __syncthreads();
        sm[t] += u;
        __syncthreads();
    }
    int excl = sm[t] - v;
    if (t < nbk) { a.base[L][t] = excl; a.cur[L][t] = excl; }
    if (t == nbk) a.base[L][t] = sm[1023];
    if (t == 0) a.offNd[L][0] = a.E[L];
}

__global__ __launch_bounds__(256) void k_cscatter(const int* __restrict__ src,
                                                  const int* __restrict__ dst,
                                                  int2* __restrict__ pairs,
                                                  int* __restrict__ ccur, int E, int shift) {
    __shared__ int scnt[1024];
    __shared__ int sbase[1024];
    for (int i = threadIdx.x; i < 1024; i += 256) scnt[i] = 0;
    __syncthreads();
    int b0 = blockIdx.x * EPB;
    int end = min(b0 + EPB, E);
    for (int i = b0 + threadIdx.x; i < end; i += 256)
        atomicAdd(&scnt[dst[i] >> shift], 1);
    __syncthreads();
    for (int i = threadIdx.x; i < 1024; i += 256) {
        int c = scnt[i];
        sbase[i] = c ? atomicAdd(&ccur[i], c) : 0;
        scnt[i] = 0;
    }
    __syncthreads();
    for (int i = b0 + threadIdx.x; i < end; i += 256) {
        int d = dst[i];
        int b = d >> shift;
        int p = sbase[b] + atomicAdd(&scnt[b], 1);
        pairs[p] = make_int2(src[i], d);
    }
}

__global__ __launch_bounds__(256) void k_fsort(const int2* __restrict__ pairs,
                                               const int* __restrict__ cbase,
                                               int* __restrict__ srt,
                                               int* __restrict__ off,
                                               int shift, int Nd) {
    int b = blockIdx.x;
    int p0 = cbase[b], p1 = cbase[b + 1];
    int width = 1 << shift;
    int mask = width - 1;
    __shared__ int fcnt[256];
    __shared__ int fbase[256];
    __shared__ int sm[256];
    int t = threadIdx.x;
    fcnt[t] = 0;
    __syncthreads();
    for (int i = p0 + t; i < p1; i += 256)
        atomicAdd(&fcnt[pairs[i].y & mask], 1);
    __syncthreads();
    int v = fcnt[t];
    sm[t] = v;
    __syncthreads();
    for (int o = 1; o < 256; o <<= 1) {
        int u = (t >= o) ? sm[t - o] : 0;
        __syncthreads();
        sm[t] += u;
        __syncthreads();
    }
    int excl = sm[t] - v;
    fbase[t] = p0 + excl;
    int d0 = b << shift;
    if (t < width && d0 + t < Nd) off[d0 + t] = p0 + excl;
    fcnt[t] = 0;
    __syncthreads();
    for (int i = p0 + t; i < p1; i += 256) {
        int2 pr = pairs[i];
        int loc = pr.y & mask;
        int pos = fbase[loc] + atomicAdd(&fcnt[loc], 1);
        srt[pos] = pr.x;
    }
}

// ---------------- weight prep: wv = Wd @ a_d per relation ----------------

struct Wv6 { const float* Wd[6]; const float* ad[6]; int K[6]; };

__global__ __launch_bounds__(64) void k_wv(Wv6 a, float* __restrict__ wv) {
    int b = blockIdx.x, t = threadIdx.x;
    if (t < a.K[b]) {
        const float* Wd = a.Wd[b];
        const float* ad = a.ad[b];
        float s = 0.f;
        for (int j = 0; j < 64; ++j) s = fmaf(Wd[t * 64 + j], ad[j], s);
        wv[b * 64 + t] = s;
    }
}

// ---------------- src GEMM: hsb = bf16(X@W) [N,64], es = (X@W)@a_s [N] ----------------
// W column in K VGPRs (loaded once per wave, amortized over 16 rows); x row
// scalarized via readfirstlane -> s_load broadcast; dual fma chains.

#define SRC_RPW 16   // rows per wave

template <int K>
__global__ __launch_bounds__(256) void k_src(const float* __restrict__ X,
                                             const float* __restrict__ W,
                                             const float* __restrict__ as_,
                                             ushort* __restrict__ hsb,
                                             float* __restrict__ es, int N) {
    int lane = threadIdx.x & 63;
    float wc[K];
#pragma unroll
    for (int k = 0; k < K; ++k) wc[k] = W[k * 64 + lane];
    float asl = as_[lane];
    int w = (blockIdx.x * 256 + threadIdx.x) >> 6;
    int r0 = w * SRC_RPW;
    int r1 = min(r0 + SRC_RPW, N);
    for (int r = r0; r < r1; ++r) {
        int ru = __builtin_amdgcn_readfirstlane(r);
        const float* xr = X + (size_t)ru * K;
        float acc0 = 0.f, acc1 = 0.f;
#pragma unroll
        for (int k = 0; k < K; k += 2) {
            acc0 = fmaf(xr[k], wc[k], acc0);
            acc1 = fmaf(xr[k + 1], wc[k + 1], acc1);
        }
        float acc = acc0 + acc1;
        hsb[(size_t)ru * 64 + lane] = f2bf(acc);
        float v = acc * asl;
#pragma unroll
        for (int o = 32; o > 0; o >>= 1) v += __shfl_xor(v, o, 64);
        if (lane == 0) es[ru] = v;
    }
}

// ---------------- pull aggregation: one wave per dst row ----------------
// 16-lane group per edge (uint2 row load), 8 edges in flight, indices cached
// from sweep 1 (no dependent srt reload). ACCUM: out += contrib (row untouched
// if no edges). !ACCUM: out = bias + contrib (bias row written even if 0 edges).

template <int K, bool ACCUM>
__global__ __launch_bounds__(256) void k_agg(const ushort* __restrict__ hsb,
                                             const float* __restrict__ es,
                                             const float* __restrict__ Xd,
                                             const float* __restrict__ wv,
                                             const float* __restrict__ bias,
                                             const int* __restrict__ off,
                                             const int* __restrict__ srt,
                                             float* __restrict__ out, int Nd) {
    int wid = (blockIdx.x * 256 + threadIdx.x) >> 6;
    int lane = threadIdx.x & 63;
    if (wid >= Nd) return;
    int s0 = off[wid], s1 = off[wid + 1];
    int n = s1 - s0;
    if (n <= 0) {
        if (!ACCUM) out[(size_t)wid * 64 + lane] = bias[lane];
        return;
    }
    // ed for this dst row (wave-uniform)
    float p = (lane < K) ? Xd[(size_t)wid * K + lane] * wv[lane] : 0.f;
#pragma unroll
    for (int o = 32; o > 0; o >>= 1) p += __shfl_xor(p, o, 64);
    float edj = p;
    // sweep 1: gather es + cache indices & leaky logits (deg<=128 in regs), wave max
    int aidx0 = 0, aidx1 = 0;
    float ev0 = -3.4e38f, ev1 = -3.4e38f;
    if (lane < n) {
        aidx0 = srt[s0 + lane];
        float e = es[aidx0] + edj;
        ev0 = e > 0.f ? e : 0.2f * e;
    }
    if (lane + 64 < n) {
        aidx1 = srt[s0 + 64 + lane];
        float e = es[aidx1] + edj;
        ev1 = e > 0.f ? e : 0.2f * e;
    }
    float m = fmaxf(ev0, ev1);
    for (int i = s0 + 128 + lane; i < s1; i += 64) {   // rare: deg > 128
        float e = es[srt[i]] + edj;
        e = e > 0.f ? e : 0.2f * e;
        m = fmaxf(m, e);
    }
#pragma unroll
    for (int o = 32; o > 0; o >>= 1) m = fmaxf(m, __shfl_xor(m, o, 64));
    // sweep 2: 16-lane group per edge, lane covers 4 bf16 channels, 8 edges/iter
    int g = lane >> 4, l16 = lane & 15;
    float a0 = 0.f, a1 = 0.f, a2 = 0.f, a3 = 0.f, den = 0.f;
    for (int i = s0; i < s1; i += 8) {
#pragma unroll
        for (int u = 0; u < 2; ++u) {
            int j = i + u * 4 + g;
            bool act = j < s1;
            int jj = j - s0;
            int idx = jj & 63;
            float eA = __shfl(ev0, idx, 64);
            float eB = __shfl(ev1, idx, 64);
            int iA = __shfl(aidx0, idx, 64);
            int iB = __shfl(aidx1, idx, 64);
            float ee = (jj < 64) ? eA : eB;
            int a = (jj < 64) ? iA : iB;
            if (jj >= 128) {       // rare fallback
                a = srt[act ? j : s0];
                float e = es[a] + edj;
                ee = e > 0.f ? e : 0.2f * e;
            }
            float w = act ? __expf(ee - m) : 0.f;
            uint2 hv = ((const uint2*)(hsb + (size_t)a * 64))[l16];
            den += w;
            a0 = fmaf(w, bf_lo(hv.x), a0);
            a1 = fmaf(w, bf_hi(hv.x), a1);
            a2 = fmaf(w, bf_lo(hv.y), a2);
            a3 = fmaf(w, bf_hi(hv.y), a3);
        }
    }
#pragma unroll
    for (int o = 16; o <= 32; o <<= 1) {
        a0 += __shfl_xor(a0, o, 64);
        a1 += __shfl_xor(a1, o, 64);
        a2 += __shfl_xor(a2, o, 64);
        a3 += __shfl_xor(a3, o, 64);
        den += __shfl_xor(den, o, 64);
    }
    float inv = 1.f / (den + 1e-16f);
    if (g == 0) {
        float4* orow = (float4*)(out + (size_t)wid * 64);
        float4 r;
        if (ACCUM) {
            float4 prev = orow[l16];
            r.x = prev.x + a0 * inv;
            r.y = prev.y + a1 * inv;
            r.z = prev.z + a2 * inv;
            r.w = prev.w + a3 * inv;
        } else {
            r.x = bias[l16 * 4 + 0] + a0 * inv;
            r.y = bias[l16 * 4 + 1] + a1 * inv;
            r.z = bias[l16 * 4 + 2] + a2 * inv;
            r.w = bias[l16 * 4 + 3] + a3 * inv;
        }
        orow[l16] = r;
    }
}

// ---------------- final FC ----------------

__global__ __launch_bounds__(256) void k_fc(const float* __restrict__ t2,
                                            const float* __restrict__ Wfc,
                                            const float* __restrict__ bfc,
                                            float* __restrict__ out, int N) {
    int wid = (blockIdx.x * 256 + threadIdx.x) >> 6;
    int lane = threadIdx.x & 63;
    if (wid >= N) return;
    float v = t2[(size_t)wid * 64 + lane];
    float p0 = v * Wfc[lane * 2 + 0];
    float p1 = v * Wfc[lane * 2 + 1];
#pragma unroll
    for (int o = 32; o > 0; o >>= 1) {
        p0 += __shfl_xor(p0, o, 64);
        p1 += __shfl_xor(p1, o, 64);
    }
    if (lane == 0) {
        out[wid * 2 + 0] = p0 + bfc[0];
        out[wid * 2 + 1] = p1 + bfc[1];
    }
}

// ---------------- launcher ----------------

extern "C" void kernel_launch(void* const* d_in, const int* in_sizes, int n_in,
                              void* d_out, int out_size, void* d_ws, size_t ws_size,
                              hipStream_t stream) {
    const float* xw = (const float*)d_in[0];
    const float* xt = (const float*)d_in[1];
    const float* xd = (const float*)d_in[2];
    const float* g1ww_Ws = (const float*)d_in[3];
    const float* g1ww_Wd = (const float*)d_in[4];
    const float* g1ww_as = (const float*)d_in[5];
    const float* g1ww_ad = (const float*)d_in[6];
    const float* g1ww_b  = (const float*)d_in[7];
    const float* g1bu_Ws = (const float*)d_in[8];
    const float* g1bu_Wd = (const float*)d_in[9];
    const float* g1bu_as = (const float*)d_in[10];
    const float* g1bu_ad = (const float*)d_in[11];
    const float* g1bu_b  = (const float*)d_in[12];
    const float* g1se_Ws = (const float*)d_in[13];
    const float* g1se_Wd = (const float*)d_in[14];
    const float* g1se_as = (const float*)d_in[15];
    const float* g1se_ad = (const float*)d_in[16];
    const float* g1se_b  = (const float*)d_in[17];
    const float* g1cr_Ws = (const float*)d_in[18];
    const float* g1cr_Wd = (const float*)d_in[19];
    const float* g1cr_as = (const float*)d_in[20];
    const float* g1cr_ad = (const float*)d_in[21];
    const float* g1cr_b  = (const float*)d_in[22];
    // d_in[23..27] = g2ww params: w2 dead in reference -> skipped
    const float* g2bu_Ws = (const float*)d_in[28];
    const float* g2bu_Wd = (const float*)d_in[29];
    const float* g2bu_as = (const float*)d_in[30];
    const float* g2bu_ad = (const float*)d_in[31];
    const float* g2bu_b  = (const float*)d_in[32];
    const float* g2se_Ws = (const float*)d_in[33];
    const float* g2se_Wd = (const float*)d_in[34];
    const float* g2se_as = (const float*)d_in[35];
    const float* g2se_ad = (const float*)d_in[36];
    const float* g2se_b  = (const float*)d_in[37];
    const float* Wfc = (const float*)d_in[38];
    const float* bfc = (const float*)d_in[39];
    const int* ww_src = (const int*)d_in[40];
    const int* ww_dst = (const int*)d_in[41];
    const int* bu_src = (const int*)d_in[42];
    const int* bu_dst = (const int*)d_in[43];
    const int* se_src = (const int*)d_in[44];
    const int* se_dst = (const int*)d_in[45];
    const int* cr_src = (const int*)d_in[46];
    const int* cr_dst = (const int*)d_in[47];

    const int totalE = EWW + EBU + ESE + ECR;

    // ---- workspace carve ----
    char* p = (char*)d_ws;
    auto alloc = [&](size_t bytes) {
        char* r = p;
        p += (bytes + 255) & ~(size_t)255;
        return r;
    };
    // region1: hsb+es+w1, aliased by build-phase pairs buffer (build finishes first)
    size_t hs_b = ((size_t)NW * 64 * 2 + 255) & ~(size_t)255;   // bf16
    size_t es_b = ((size_t)NW * 4 + 255) & ~(size_t)255;
    size_t w1_b = ((size_t)NW * 64 * 4 + 255) & ~(size_t)255;
    size_t pairs_b = ((size_t)totalE * 8 + 255) & ~(size_t)255;
    size_t r1_b = hs_b + es_b + w1_b;
    if (pairs_b > r1_b) r1_b = pairs_b;
    char* r1 = alloc(r1_b);
    ushort* hsb = (ushort*)r1;
    float* es = (float*)(r1 + hs_b);
    float* w1 = (float*)(r1 + hs_b + es_b);
    int2* pairsW = (int2*)r1;
    int2* pairsB = pairsW + EWW;
    int2* pairsS = pairsB + EBU;
    int2* pairsC = pairsS + ESE;

    float* t1 = (float*)alloc((size_t)NT * 64 * 4);
    float* t2 = (float*)alloc((size_t)NT * 64 * 4);
    float* wv = (float*)alloc(6 * 64 * 4);
    float* biasT1 = (float*)alloc(64 * 4);
    float* biasT2 = (float*)alloc(64 * 4);
    int* ccnt  = (int*)alloc(4 * 1024 * 4);
    int* cbase = (int*)alloc(4 * 1025 * 4);
    int* ccur  = (int*)alloc(4 * 1024 * 4);
    int* offW = (int*)alloc((size_t)(NW + 1) * 4);
    int* offB = (int*)alloc((size_t)(NT + 1) * 4);
    int* offS = (int*)alloc((size_t)(NT + 1) * 4);
    int* offC = (int*)alloc((size_t)(NT + 1) * 4);
    int* srtW = (int*)alloc((size_t)EWW * 4);
    int* srtB = (int*)alloc((size_t)EBU * 4);
    int* srtS = (int*)alloc((size_t)ESE * 4);
    int* srtC = (int*)alloc((size_t)ECR * 4);

    const int thr = 256;
    const int SHW = 8, NBW = (NW + 255) / 256;   // 391 buckets of 256
    const int SHT = 6, NBT = (NT + 63) / 64;     // 313 buckets of 64
    const int RPB = SRC_RPW * 4;                 // rows per k_src block

    // ---- CSR build ----
    k_zero<<<(4 * 1024 + thr - 1) / thr, thr, 0, stream>>>(ccnt, 4 * 1024);

    k_chist<<<(EWW + EPB - 1) / EPB, thr, 0, stream>>>(ww_dst, ccnt + 0 * 1024, EWW, SHW);
    k_chist<<<(EBU + EPB - 1) / EPB, thr, 0, stream>>>(bu_dst, ccnt + 1 * 1024, EBU, SHT);
    k_chist<<<(ESE + EPB - 1) / EPB, thr, 0, stream>>>(se_dst, ccnt + 2 * 1024, ESE, SHT);
    k_chist<<<(ECR + EPB - 1) / EPB, thr, 0, stream>>>(cr_dst, ccnt + 3 * 1024, ECR, SHT);

    CScan cs;
    cs.cnt[0] = ccnt + 0 * 1024; cs.base[0] = cbase + 0 * 1025; cs.cur[0] = ccur + 0 * 1024;
    cs.offNd[0] = offW + NW; cs.nbk[0] = NBW; cs.E[0] = EWW;
    cs.cnt[1] = ccnt + 1 * 1024; cs.base[1] = cbase + 1 * 1025; cs.cur[1] = ccur + 1 * 1024;
    cs.offNd[1] = offB + NT; cs.nbk[1] = NBT; cs.E[1] = EBU;
    cs.cnt[2] = ccnt + 2 * 1024; cs.base[2] = cbase + 2 * 1025; cs.cur[2] = ccur + 2 * 1024;
    cs.offNd[2] = offS + NT; cs.nbk[2] = NBT; cs.E[2] = ESE;
    cs.cnt[3] = ccnt + 3 * 1024; cs.base[3] = cbase + 3 * 1025; cs.cur[3] = ccur + 3 * 1024;
    cs.offNd[3] = offC + NT; cs.nbk[3] = NBT; cs.E[3] = ECR;
    k_cscan<<<4, 1024, 0, stream>>>(cs);

    k_cscatter<<<(EWW + EPB - 1) / EPB, thr, 0, stream>>>(ww_src, ww_dst, pairsW, ccur + 0 * 1024, EWW, SHW);
    k_cscatter<<<(EBU + EPB - 1) / EPB, thr, 0, stream>>>(bu_src, bu_dst, pairsB, ccur + 1 * 1024, EBU, SHT);
    k_cscatter<<<(ESE + EPB - 1) / EPB, thr, 0, stream>>>(se_src, se_dst, pairsS, ccur + 2 * 1024, ESE, SHT);
    k_cscatter<<<(ECR + EPB - 1) / EPB, thr, 0, stream>>>(cr_src, cr_dst, pairsC, ccur + 3 * 1024, ECR, SHT);

    k_fsort<<<NBW, thr, 0, stream>>>(pairsW, cbase + 0 * 1025, srtW, offW, SHW, NW);
    k_fsort<<<NBT, thr, 0, stream>>>(pairsB, cbase + 1 * 1025, srtB, offB, SHT, NT);
    k_fsort<<<NBT, thr, 0, stream>>>(pairsS, cbase + 2 * 1025, srtS, offS, SHT, NT);
    k_fsort<<<NBT, thr, 0, stream>>>(pairsC, cbase + 3 * 1025, srtC, offC, SHT, NT);

    // ---- wv = Wd @ a_d + combined biases ----
    Wv6 wa;
    wa.Wd[0] = g1ww_Wd; wa.ad[0] = g1ww_ad; wa.K[0] = 32;
    wa.Wd[1] = g1bu_Wd; wa.ad[1] = g1bu_ad; wa.K[1] = 32;
    wa.Wd[2] = g1se_Wd; wa.ad[2] = g1se_ad; wa.K[2] = 32;
    wa.Wd[3] = g1cr_Wd; wa.ad[3] = g1cr_ad; wa.K[3] = 32;
    wa.Wd[4] = g2bu_Wd; wa.ad[4] = g2bu_ad; wa.K[4] = 64;
    wa.Wd[5] = g2se_Wd; wa.ad[5] = g2se_ad; wa.K[5] = 64;
    k_wv<<<6, 64, 0, stream>>>(wa, wv);
    k_bsum<<<1, 64, 0, stream>>>(g1bu_b, g1se_b, g1cr_b, biasT1);
    k_bsum<<<1, 64, 0, stream>>>(g2bu_b, g2se_b, nullptr, biasT2);

    // ---- layer 1 ----
    k_src<32><<<(NW + RPB - 1) / RPB, thr, 0, stream>>>(xw, g1ww_Ws, g1ww_as, hsb, es, NW);
    k_agg<32, false><<<(NW + 3) / 4, thr, 0, stream>>>(hsb, es, xw, wv + 0 * 64, g1ww_b, offW, srtW, w1, NW);
    k_src<32><<<(NW + RPB - 1) / RPB, thr, 0, stream>>>(xw, g1bu_Ws, g1bu_as, hsb, es, NW);
    k_agg<32, false><<<(NT + 3) / 4, thr, 0, stream>>>(hsb, es, xt, wv + 1 * 64, biasT1, offB, srtB, t1, NT);
    k_src<32><<<(NW + RPB - 1) / RPB, thr, 0, stream>>>(xw, g1se_Ws, g1se_as, hsb, es, NW);
    k_agg<32, true><<<(NT + 3) / 4, thr, 0, stream>>>(hsb, es, xt, wv + 2 * 64, nullptr, offS, srtS, t1, NT);
    k_src<16><<<(ND + RPB - 1) / RPB, thr, 0, stream>>>(xd, g1cr_Ws, g1cr_as, hsb, es, ND);
    k_agg<32, true><<<(NT + 3) / 4, thr, 0, stream>>>(hsb, es, xt, wv + 3 * 64, nullptr, offC, srtC, t1, NT);

    // ---- layer 2 (w2 dead -> skipped) ----
    k_src<64><<<(NW + RPB - 1) / RPB, thr, 0, stream>>>(w1, g2bu_Ws, g2bu_as, hsb, es, NW);
    k_agg<64, false><<<(NT + 3) / 4, thr, 0, stream>>>(hsb, es, t1, wv + 4 * 64, biasT2, offB, srtB, t2, NT);
    k_src<64><<<(NW + RPB - 1) / RPB, thr, 0, stream>>>(w1, g2se_Ws, g2se_as, hsb, es, NW);
    k_agg<64, true><<<(NT + 3) / 4, thr, 0, stream>>>(hsb, es, t1, wv + 5 * 64, nullptr, offS, srtS, t2, NT);

    // ---- final FC ----
    k_fc<<<(NT + 3) / 4, thr, 0, stream>>>(t2, Wfc, bfc, (float*)d_out, NT);
}

// Round 6
// 558.815 us; speedup vs baseline: 2.7306x; 1.3900x over previous
//
#include <hip/hip_runtime.h>

#define NW 100000
#define NT 20000
#define ND 5000
#define EWW 1600000
#define EBU 1000000
#define ESE 1000000
#define ECR 20000
#define EPB 8192     // edges per block for coarse hist/scatter
#define BTH 512      // threads for build kernels

typedef unsigned int uint;
typedef unsigned short ushort;

__device__ __forceinline__ float bf_lo(uint v) { return __builtin_bit_cast(float, v << 16); }
__device__ __forceinline__ float bf_hi(uint v) { return __builtin_bit_cast(float, v & 0xffff0000u); }
__device__ __forceinline__ ushort f2bf(float x) {
    uint b = __builtin_bit_cast(uint, x);
    return (ushort)((b + 0x7fffu + ((b >> 16) & 1u)) >> 16);  // RNE
}

// ---------------- utility kernels ----------------

__global__ void k_zero(int* __restrict__ p, int n) {
    int t = blockIdx.x * blockDim.x + threadIdx.x;
    if (t < n) p[t] = 0;
}

__global__ __launch_bounds__(64) void k_bsum(const float* __restrict__ b0,
                                             const float* __restrict__ b1,
                                             const float* __restrict__ b2,
                                             float* __restrict__ out) {
    int t = threadIdx.x;
    float v = b0[t] + b1[t];
    if (b2) v += b2[t];
    out[t] = v;
}

// ---------------- CSR build: two-level counting sort, 4 lists fused ----------------
// pairs packed: src (20 bits) | dstLocal << 20 (<=8 bits)

struct BMeta {
    const int* src[4]; const int* dst[4];
    int* ccnt[4]; int* ccur[4];
    uint* pairs[4];
    int E[4]; int shift[4]; int bbase[5];
};

__device__ __forceinline__ int find_list(const int* bbase, int b) {
    int li = 0;
    while (li < 3 && b >= bbase[li + 1]) ++li;
    return li;
}

__global__ __launch_bounds__(BTH) void k_chist4(BMeta a) {
    __shared__ int sc[1024];
    for (int i = threadIdx.x; i < 1024; i += BTH) sc[i] = 0;
    __syncthreads();
    int li = find_list(a.bbase, blockIdx.x);
    int lb = blockIdx.x - a.bbase[li];
    const int* dst = a.dst[li];
    int sh = a.shift[li];
    int b0 = lb * EPB;
    int end = min(b0 + EPB, a.E[li]);
    for (int i = b0 + threadIdx.x; i < end; i += BTH)
        atomicAdd(&sc[dst[i] >> sh], 1);
    __syncthreads();
    int* ccnt = a.ccnt[li];
    for (int i = threadIdx.x; i < 1024; i += BTH)
        if (sc[i]) atomicAdd(&ccnt[i], sc[i]);
}

__global__ __launch_bounds__(BTH) void k_cscat4(BMeta a) {
    __shared__ int scnt[1024];
    __shared__ int sbase[1024];
    for (int i = threadIdx.x; i < 1024; i += BTH) scnt[i] = 0;
    __syncthreads();
    int li = find_list(a.bbase, blockIdx.x);
    int lb = blockIdx.x - a.bbase[li];
    const int* src = a.src[li];
    const int* dst = a.dst[li];
    uint* pairs = a.pairs[li];
    int* ccur = a.ccur[li];
    int sh = a.shift[li];
    uint mask = (1u << sh) - 1u;
    int b0 = lb * EPB;
    int end = min(b0 + EPB, a.E[li]);
    for (int i = b0 + threadIdx.x; i < end; i += BTH)
        atomicAdd(&scnt[dst[i] >> sh], 1);
    __syncthreads();
    for (int i = threadIdx.x; i < 1024; i += BTH) {
        int c = scnt[i];
        sbase[i] = c ? atomicAdd(&ccur[i], c) : 0;
        scnt[i] = 0;   // becomes local cursor
    }
    __syncthreads();
    for (int i = b0 + threadIdx.x; i < end; i += BTH) {
        int d = dst[i];
        int b = d >> sh;
        int p = sbase[b] + atomicAdd(&scnt[b], 1);
        pairs[p] = (uint)src[i] | (((uint)d & mask) << 20);
    }
}

struct CScan {
    const int* cnt[4]; int* base[4]; int* cur[4]; int* offNd[4];
    int nbk[4]; int E[4];
};
__global__ __launch_bounds__(1024) void k_cscan(CScan a) {
    int L = blockIdx.x;
    __shared__ int sm[1024];
    int t = threadIdx.x;
    int nbk = a.nbk[L];
    int v = (t < nbk) ? a.cnt[L][t] : 0;
    sm[t] = v;
    __syncthreads();
    for (int o = 1; o < 1024; o <<= 1) {
        int u = (t >= o) ? sm[t - o] : 0;
        __syncthreads();
        sm[t] += u;
        __syncthreads();
    }
    int excl = sm[t] - v;
    if (t < nbk) { a.base[L][t] = excl; a.cur[L][t] = excl; }
    if (t == nbk) a.base[L][t] = sm[1023];
    if (t == 0) a.offNd[L][0] = a.E[L];
}

// fine sort: one block per coarse bucket, 4 lists fused
struct FMeta {
    const uint* pairs[4]; const int* cbase[4];
    int* srt[4]; int* off[4];
    int shift[4]; int Nd[4]; int bbase[5];
};

__global__ __launch_bounds__(256) void k_fsort4(FMeta a) {
    int li = find_list(a.bbase, blockIdx.x);
    int b = blockIdx.x - a.bbase[li];
    const uint* pairs = a.pairs[li];
    const int* cbase = a.cbase[li];
    int* srt = a.srt[li];
    int* off = a.off[li];
    int shift = a.shift[li];
    int Nd = a.Nd[li];
    int p0 = cbase[b], p1 = cbase[b + 1];
    int width = 1 << shift;
    __shared__ int fcnt[256];
    __shared__ int fbase[256];
    __shared__ int sm[256];
    int t = threadIdx.x;
    fcnt[t] = 0;
    __syncthreads();
    for (int i = p0 + t; i < p1; i += 256)
        atomicAdd(&fcnt[pairs[i] >> 20], 1);
    __syncthreads();
    int v = fcnt[t];
    sm[t] = v;
    __syncthreads();
    for (int o = 1; o < 256; o <<= 1) {
        int u = (t >= o) ? sm[t - o] : 0;
        __syncthreads();
        sm[t] += u;
        __syncthreads();
    }
    int excl = sm[t] - v;
    fbase[t] = p0 + excl;
    int d0 = b << shift;
    if (t < width && d0 + t < Nd) off[d0 + t] = p0 + excl;
    fcnt[t] = 0;
    __syncthreads();
    for (int i = p0 + t; i < p1; i += 256) {
        uint pr = pairs[i];
        int loc = pr >> 20;
        int pos = fbase[loc] + atomicAdd(&fcnt[loc], 1);
        srt[pos] = (int)(pr & 0xFFFFFu);
    }
}

// ---------------- weight prep: wv = Wd @ a_d per relation ----------------

struct Wv6 { const float* Wd[6]; const float* ad[6]; int K[6]; };

__global__ __launch_bounds__(64) void k_wv(Wv6 a, float* __restrict__ wv) {
    int b = blockIdx.x, t = threadIdx.x;
    if (t < a.K[b]) {
        const float* Wd = a.Wd[b];
        const float* ad = a.ad[b];
        float s = 0.f;
        for (int j = 0; j < 64; ++j) s = fmaf(Wd[t * 64 + j], ad[j], s);
        wv[b * 64 + t] = s;
    }
}

// ---------------- src GEMM: hsb = bf16(X@W) [N,64], es = (X@W)@a_s [N] ----------------

#define SRC_RPW 16   // rows per wave

template <int K>
__global__ __launch_bounds__(256) void k_src(const float* __restrict__ X,
                                             const float* __restrict__ W,
                                             const float* __restrict__ as_,
                                             ushort* __restrict__ hsb,
                                             float* __restrict__ es, int N) {
    int lane = threadIdx.x & 63;
    float wc[K];
#pragma unroll
    for (int k = 0; k < K; ++k) wc[k] = W[k * 64 + lane];
    float asl = as_[lane];
    int w = (blockIdx.x * 256 + threadIdx.x) >> 6;
    int r0 = w * SRC_RPW;
    int r1 = min(r0 + SRC_RPW, N);
    for (int r = r0; r < r1; ++r) {
        int ru = __builtin_amdgcn_readfirstlane(r);
        const float* xr = X + (size_t)ru * K;
        float acc0 = 0.f, acc1 = 0.f;
#pragma unroll
        for (int k = 0; k < K; k += 2) {
            acc0 = fmaf(xr[k], wc[k], acc0);
            acc1 = fmaf(xr[k + 1], wc[k + 1], acc1);
        }
        float acc = acc0 + acc1;
        hsb[(size_t)ru * 64 + lane] = f2bf(acc);
        float v = acc * asl;
#pragma unroll
        for (int o = 32; o > 0; o >>= 1) v += __shfl_xor(v, o, 64);
        if (lane == 0) es[ru] = v;
    }
}

// ---------------- pull aggregation: one wave per dst row ----------------

template <int K, bool ACCUM>
__global__ __launch_bounds__(256) void k_agg(const ushort* __restrict__ hsb,
                                             const float* __restrict__ es,
                                             const float* __restrict__ Xd,
                                             const float* __restrict__ wv,
                                             const float* __restrict__ bias,
                                             const int* __restrict__ off,
                                             const int* __restrict__ srt,
                                             float* __restrict__ out, int Nd) {
    int wid = (blockIdx.x * 256 + threadIdx.x) >> 6;
    int lane = threadIdx.x & 63;
    if (wid >= Nd) return;
    int s0 = off[wid], s1 = off[wid + 1];
    int n = s1 - s0;
    if (n <= 0) {
        if (!ACCUM) out[(size_t)wid * 64 + lane] = bias[lane];
        return;
    }
    float p = (lane < K) ? Xd[(size_t)wid * K + lane] * wv[lane] : 0.f;
#pragma unroll
    for (int o = 32; o > 0; o >>= 1) p += __shfl_xor(p, o, 64);
    float edj = p;
    int aidx0 = 0, aidx1 = 0;
    float ev0 = -3.4e38f, ev1 = -3.4e38f;
    if (lane < n) {
        aidx0 = srt[s0 + lane];
        float e = es[aidx0] + edj;
        ev0 = e > 0.f ? e : 0.2f * e;
    }
    if (lane + 64 < n) {
        aidx1 = srt[s0 + 64 + lane];
        float e = es[aidx1] + edj;
        ev1 = e > 0.f ? e : 0.2f * e;
    }
    float m = fmaxf(ev0, ev1);
    for (int i = s0 + 128 + lane; i < s1; i += 64) {
        float e = es[srt[i]] + edj;
        e = e > 0.f ? e : 0.2f * e;
        m = fmaxf(m, e);
    }
#pragma unroll
    for (int o = 32; o > 0; o >>= 1) m = fmaxf(m, __shfl_xor(m, o, 64));
    int g = lane >> 4, l16 = lane & 15;
    float a0 = 0.f, a1 = 0.f, a2 = 0.f, a3 = 0.f, den = 0.f;
    for (int i = s0; i < s1; i += 8) {
#pragma unroll
        for (int u = 0; u < 2; ++u) {
            int j = i + u * 4 + g;
            bool act = j < s1;
            int jj = j - s0;
            int idx = jj & 63;
            float eA = __shfl(ev0, idx, 64);
            float eB = __shfl(ev1, idx, 64);
            int iA = __shfl(aidx0, idx, 64);
            int iB = __shfl(aidx1, idx, 64);
            float ee = (jj < 64) ? eA : eB;
            int a = (jj < 64) ? iA : iB;
            if (jj >= 128) {
                a = srt[act ? j : s0];
                float e = es[a] + edj;
                ee = e > 0.f ? e : 0.2f * e;
            }
            float w = act ? __expf(ee - m) : 0.f;
            uint2 hv = ((const uint2*)(hsb + (size_t)a * 64))[l16];
            den += w;
            a0 = fmaf(w, bf_lo(hv.x), a0);
            a1 = fmaf(w, bf_hi(hv.x), a1);
            a2 = fmaf(w, bf_lo(hv.y), a2);
            a3 = fmaf(w, bf_hi(hv.y), a3);
        }
    }
#pragma unroll
    for (int o = 16; o <= 32; o <<= 1) {
        a0 += __shfl_xor(a0, o, 64);
        a1 += __shfl_xor(a1, o, 64);
        a2 += __shfl_xor(a2, o, 64);
        a3 += __shfl_xor(a3, o, 64);
        den += __shfl_xor(den, o, 64);
    }
    float inv = 1.f / (den + 1e-16f);
    if (g == 0) {
        float4* orow = (float4*)(out + (size_t)wid * 64);
        float4 r;
        if (ACCUM) {
            float4 prev = orow[l16];
            r.x = prev.x + a0 * inv;
            r.y = prev.y + a1 * inv;
            r.z = prev.z + a2 * inv;
            r.w = prev.w + a3 * inv;
        } else {
            r.x = bias[l16 * 4 + 0] + a0 * inv;
            r.y = bias[l16 * 4 + 1] + a1 * inv;
            r.z = bias[l16 * 4 + 2] + a2 * inv;
            r.w = bias[l16 * 4 + 3] + a3 * inv;
        }
        orow[l16] = r;
    }
}

// ---------------- final FC ----------------

__global__ __launch_bounds__(256) void k_fc(const float* __restrict__ t2,
                                            const float* __restrict__ Wfc,
                                            const float* __restrict__ bfc,
                                            float* __restrict__ out, int N) {
    int wid = (blockIdx.x * 256 + threadIdx.x) >> 6;
    int lane = threadIdx.x & 63;
    if (wid >= N) return;
    float v = t2[(size_t)wid * 64 + lane];
    float p0 = v * Wfc[lane * 2 + 0];
    float p1 = v * Wfc[lane * 2 + 1];
#pragma unroll
    for (int o = 32; o > 0; o >>= 1) {
        p0 += __shfl_xor(p0, o, 64);
        p1 += __shfl_xor(p1, o, 64);
    }
    if (lane == 0) {
        out[wid * 2 + 0] = p0 + bfc[0];
        out[wid * 2 + 1] = p1 + bfc[1];
    }
}

// ---------------- launcher ----------------

extern "C" void kernel_launch(void* const* d_in, const int* in_sizes, int n_in,
                              void* d_out, int out_size, void* d_ws, size_t ws_size,
                              hipStream_t stream) {
    const float* xw = (const float*)d_in[0];
    const float* xt = (const float*)d_in[1];
    const float* xd = (const float*)d_in[2];
    const float* g1ww_Ws = (const float*)d_in[3];
    const float* g1ww_Wd = (const float*)d_in[4];
    const float* g1ww_as = (const float*)d_in[5];
    const float* g1ww_ad = (const float*)d_in[6];
    const float* g1ww_b  = (const float*)d_in[7];
    const float* g1bu_Ws = (const float*)d_in[8];
    const float* g1bu_Wd = (const float*)d_in[9];
    const float* g1bu_as = (const float*)d_in[10];
    const float* g1bu_ad = (const float*)d_in[11];
    const float* g1bu_b  = (const float*)d_in[12];
    const float* g1se_Ws = (const float*)d_in[13];
    const float* g1se_Wd = (const float*)d_in[14];
    const float* g1se_as = (const float*)d_in[15];
    const float* g1se_ad = (const float*)d_in[16];
    const float* g1se_b  = (const float*)d_in[17];
    const float* g1cr_Ws = (const float*)d_in[18];
    const float* g1cr_Wd = (const float*)d_in[19];
    const float* g1cr_as = (const float*)d_in[20];
    const float* g1cr_ad = (const float*)d_in[21];
    const float* g1cr_b  = (const float*)d_in[22];
    // d_in[23..27] = g2ww params: w2 dead in reference -> skipped
    const float* g2bu_Ws = (const float*)d_in[28];
    const float* g2bu_Wd = (const float*)d_in[29];
    const float* g2bu_as = (const float*)d_in[30];
    const float* g2bu_ad = (const float*)d_in[31];
    const float* g2bu_b  = (const float*)d_in[32];
    const float* g2se_Ws = (const float*)d_in[33];
    const float* g2se_Wd = (const float*)d_in[34];
    const float* g2se_as = (const float*)d_in[35];
    const float* g2se_ad = (const float*)d_in[36];
    const float* g2se_b  = (const float*)d_in[37];
    const float* Wfc = (const float*)d_in[38];
    const float* bfc = (const float*)d_in[39];
    const int* ww_src = (const int*)d_in[40];
    const int* ww_dst = (const int*)d_in[41];
    const int* bu_src = (const int*)d_in[42];
    const int* bu_dst = (const int*)d_in[43];
    const int* se_src = (const int*)d_in[44];
    const int* se_dst = (const int*)d_in[45];
    const int* cr_src = (const int*)d_in[46];
    const int* cr_dst = (const int*)d_in[47];

    // ---- workspace carve ----
    char* p = (char*)d_ws;
    auto alloc = [&](size_t bytes) {
        char* r = p;
        p += (bytes + 255) & ~(size_t)255;
        return r;
    };
    // region1: hsb+es+w1 aliased by build-phase packed-pairs buffer
    size_t hs_b = ((size_t)NW * 64 * 2 + 255) & ~(size_t)255;   // bf16
    size_t es_b = ((size_t)NW * 4 + 255) & ~(size_t)255;
    size_t w1_b = ((size_t)NW * 64 * 4 + 255) & ~(size_t)255;
    const int totalE = EWW + EBU + ESE + ECR;
    size_t pairs_b = ((size_t)totalE * 4 + 255) & ~(size_t)255;
    size_t r1_b = hs_b + es_b + w1_b;
    if (pairs_b > r1_b) r1_b = pairs_b;
    char* r1 = alloc(r1_b);
    ushort* hsb = (ushort*)r1;
    float* es = (float*)(r1 + hs_b);
    float* w1 = (float*)(r1 + hs_b + es_b);
    uint* pairsW = (uint*)r1;
    uint* pairsB = pairsW + EWW;
    uint* pairsS = pairsB + EBU;
    uint* pairsC = pairsS + ESE;

    float* t1 = (float*)alloc((size_t)NT * 64 * 4);
    float* t2 = (float*)alloc((size_t)NT * 64 * 4);
    float* wv = (float*)alloc(6 * 64 * 4);
    float* biasT1 = (float*)alloc(64 * 4);
    float* biasT2 = (float*)alloc(64 * 4);
    int* ccnt  = (int*)alloc(4 * 1024 * 4);
    int* cbase = (int*)alloc(4 * 1025 * 4);
    int* ccur  = (int*)alloc(4 * 1024 * 4);
    int* offW = (int*)alloc((size_t)(NW + 1) * 4);
    int* offB = (int*)alloc((size_t)(NT + 1) * 4);
    int* offS = (int*)alloc((size_t)(NT + 1) * 4);
    int* offC = (int*)alloc((size_t)(NT + 1) * 4);
    int* srtW = (int*)alloc((size_t)EWW * 4);
    int* srtB = (int*)alloc((size_t)EBU * 4);
    int* srtS = (int*)alloc((size_t)ESE * 4);
    int* srtC = (int*)alloc((size_t)ECR * 4);

    const int thr = 256;
    const int SHW = 8, NBW = (NW + 255) / 256;   // 391 buckets of 256
    const int SHT = 6, NBT = (NT + 63) / 64;     // 313 buckets of 64
    const int RPB = SRC_RPW * 4;                 // rows per k_src block

    // per-list build blocks
    const int nbW = (EWW + EPB - 1) / EPB;       // 196
    const int nbB = (EBU + EPB - 1) / EPB;       // 123
    const int nbS = (ESE + EPB - 1) / EPB;       // 123
    const int nbC = (ECR + EPB - 1) / EPB;       // 3
    const int nbTot = nbW + nbB + nbS + nbC;     // 445

    // ---- CSR build ----
    k_zero<<<(4 * 1024 + thr - 1) / thr, thr, 0, stream>>>(ccnt, 4 * 1024);

    BMeta bm;
    bm.src[0] = ww_src; bm.dst[0] = ww_dst; bm.ccnt[0] = ccnt + 0 * 1024; bm.ccur[0] = ccur + 0 * 1024;
    bm.pairs[0] = pairsW; bm.E[0] = EWW; bm.shift[0] = SHW;
    bm.src[1] = bu_src; bm.dst[1] = bu_dst; bm.ccnt[1] = ccnt + 1 * 1024; bm.ccur[1] = ccur + 1 * 1024;
    bm.pairs[1] = pairsB; bm.E[1] = EBU; bm.shift[1] = SHT;
    bm.src[2] = se_src; bm.dst[2] = se_dst; bm.ccnt[2] = ccnt + 2 * 1024; bm.ccur[2] = ccur + 2 * 1024;
    bm.pairs[2] = pairsS; bm.E[2] = ESE; bm.shift[2] = SHT;
    bm.src[3] = cr_src; bm.dst[3] = cr_dst; bm.ccnt[3] = ccnt + 3 * 1024; bm.ccur[3] = ccur + 3 * 1024;
    bm.pairs[3] = pairsC; bm.E[3] = ECR; bm.shift[3] = SHT;
    bm.bbase[0] = 0; bm.bbase[1] = nbW; bm.bbase[2] = nbW + nbB;
    bm.bbase[3] = nbW + nbB + nbS; bm.bbase[4] = nbTot;

    k_chist4<<<nbTot, BTH, 0, stream>>>(bm);

    CScan cs;
    cs.cnt[0] = ccnt + 0 * 1024; cs.base[0] = cbase + 0 * 1025; cs.cur[0] = ccur + 0 * 1024;
    cs.offNd[0] = offW + NW; cs.nbk[0] = NBW; cs.E[0] = EWW;
    cs.cnt[1] = ccnt + 1 * 1024; cs.base[1] = cbase + 1 * 1025; cs.cur[1] = ccur + 1 * 1024;
    cs.offNd[1] = offB + NT; cs.nbk[1] = NBT; cs.E[1] = EBU;
    cs.cnt[2] = ccnt + 2 * 1024; cs.base[2] = cbase + 2 * 1025; cs.cur[2] = ccur + 2 * 1024;
    cs.offNd[2] = offS + NT; cs.nbk[2] = NBT; cs.E[2] = ESE;
    cs.cnt[3] = ccnt + 3 * 1024; cs.base[3] = cbase + 3 * 1025; cs.cur[3] = ccur + 3 * 1024;
    cs.offNd[3] = offC + NT; cs.nbk[3] = NBT; cs.E[3] = ECR;
    k_cscan<<<4, 1024, 0, stream>>>(cs);

    k_cscat4<<<nbTot, BTH, 0, stream>>>(bm);

    FMeta fm;
    fm.pairs[0] = pairsW; fm.cbase[0] = cbase + 0 * 1025; fm.srt[0] = srtW; fm.off[0] = offW;
    fm.shift[0] = SHW; fm.Nd[0] = NW;
    fm.pairs[1] = pairsB; fm.cbase[1] = cbase + 1 * 1025; fm.srt[1] = srtB; fm.off[1] = offB;
    fm.shift[1] = SHT; fm.Nd[1] = NT;
    fm.pairs[2] = pairsS; fm.cbase[2] = cbase + 2 * 1025; fm.srt[2] = srtS; fm.off[2] = offS;
    fm.shift[2] = SHT; fm.Nd[2] = NT;
    fm.pairs[3] = pairsC; fm.cbase[3] = cbase + 3 * 1025; fm.srt[3] = srtC; fm.off[3] = offC;
    fm.shift[3] = SHT; fm.Nd[3] = NT;
    fm.bbase[0] = 0; fm.bbase[1] = NBW; fm.bbase[2] = NBW + NBT;
    fm.bbase[3] = NBW + 2 * NBT; fm.bbase[4] = NBW + 3 * NBT;
    k_fsort4<<<NBW + 3 * NBT, thr, 0, stream>>>(fm);

    // ---- wv = Wd @ a_d + combined biases ----
    Wv6 wa;
    wa.Wd[0] = g1ww_Wd; wa.ad[0] = g1ww_ad; wa.K[0] = 32;
    wa.Wd[1] = g1bu_Wd; wa.ad[1] = g1bu_ad; wa.K[1] = 32;
    wa.Wd[2] = g1se_Wd; wa.ad[2] = g1se_ad; wa.K[2] = 32;
    wa.Wd[3] = g1cr_Wd; wa.ad[3] = g1cr_ad; wa.K[3] = 32;
    wa.Wd[4] = g2bu_Wd; wa.ad[4] = g2bu_ad; wa.K[4] = 64;
    wa.Wd[5] = g2se_Wd; wa.ad[5] = g2se_ad; wa.K[5] = 64;
    k_wv<<<6, 64, 0, stream>>>(wa, wv);
    k_bsum<<<1, 64, 0, stream>>>(g1bu_b, g1se_b, g1cr_b, biasT1);
    k_bsum<<<1, 64, 0, stream>>>(g2bu_b, g2se_b, nullptr, biasT2);

    // ---- layer 1 ----
    k_src<32><<<(NW + RPB - 1) / RPB, thr, 0, stream>>>(xw, g1ww_Ws, g1ww_as, hsb, es, NW);
    k_agg<32, false><<<(NW + 3) / 4, thr, 0, stream>>>(hsb, es, xw, wv + 0 * 64, g1ww_b, offW, srtW, w1, NW);
    k_src<32><<<(NW + RPB - 1) / RPB, thr, 0, stream>>>(xw, g1bu_Ws, g1bu_as, hsb, es, NW);
    k_agg<32, false><<<(NT + 3) / 4, thr, 0, stream>>>(hsb, es, xt, wv + 1 * 64, biasT1, offB, srtB, t1, NT);
    k_src<32><<<(NW + RPB - 1) / RPB, thr, 0, stream>>>(xw, g1se_Ws, g1se_as, hsb, es, NW);
    k_agg<32, true><<<(NT + 3) / 4, thr, 0, stream>>>(hsb, es, xt, wv + 2 * 64, nullptr, offS, srtS, t1, NT);
    k_src<16><<<(ND + RPB - 1) / RPB, thr, 0, stream>>>(xd, g1cr_Ws, g1cr_as, hsb, es, ND);
    k_agg<32, true><<<(NT + 3) / 4, thr, 0, stream>>>(hsb, es, xt, wv + 3 * 64, nullptr, offC, srtC, t1, NT);

    // ---- layer 2 (w2 dead -> skipped) ----
    k_src<64><<<(NW + RPB - 1) / RPB, thr, 0, stream>>>(w1, g2bu_Ws, g2bu_as, hsb, es, NW);
    k_agg<64, false><<<(NT + 3) / 4, thr, 0, stream>>>(hsb, es, t1, wv + 4 * 64, biasT2, offB, srtB, t2, NT);
    k_src<64><<<(NW + RPB - 1) / RPB, thr, 0, stream>>>(w1, g2se_Ws, g2se_as, hsb, es, NW);
    k_agg<64, true><<<(NT + 3) / 4, thr, 0, stream>>>(hsb, es, t1, wv + 5 * 64, nullptr, offS, srtS, t2, NT);

    // ---- final FC ----
    k_fc<<<(NT + 3) / 4, thr, 0, stream>>>(t2, Wfc, bfc, (float*)d_out, NT);
}

// Round 7
// 469.180 us; speedup vs baseline: 3.2523x; 1.1910x over previous
//
#include <hip/hip_runtime.h>

#define NW 100000
#define NT 20000
#define ND 5000
#define EWW 1600000
#define EBU 1000000
#define ESE 1000000
#define ECR 20000
#define EPB 8192     // edges per block for coarse hist/scatter
#define BTH 512      // threads for build kernels
#define SRC_RPW 16   // rows per wave in post-GEMMs

typedef unsigned int uint;
typedef unsigned short ushort;

__device__ __forceinline__ float bf_lo(uint v) { return __builtin_bit_cast(float, v << 16); }
__device__ __forceinline__ float bf_hi(uint v) { return __builtin_bit_cast(float, v & 0xffff0000u); }
__device__ __forceinline__ ushort f2bf(float x) {
    uint b = __builtin_bit_cast(uint, x);
    return (ushort)((b + 0x7fffu + ((b >> 16) & 1u)) >> 16);  // RNE
}

// ---------------- utility ----------------

__global__ void k_zero(int* __restrict__ p, int n) {
    int t = blockIdx.x * blockDim.x + threadIdx.x;
    if (t < n) p[t] = 0;
}

__global__ __launch_bounds__(64) void k_bsum(const float* __restrict__ b0,
                                             const float* __restrict__ b1,
                                             const float* __restrict__ b2,
                                             float* __restrict__ out) {
    int t = threadIdx.x;
    float v = b0[t] + b1[t];
    if (b2) v += b2[t];
    out[t] = v;
}

// ---------------- CSR build: two-level counting sort, 4 lists fused ----------------
// pairs packed: src (20 bits) | dstLocal << 20 (<=8 bits)

struct BMeta {
    const int* src[4]; const int* dst[4];
    int* ccnt[4]; int* ccur[4];
    uint* pairs[4];
    int E[4]; int shift[4]; int bbase[5];
};

__device__ __forceinline__ int find_list(const int* bbase, int b) {
    int li = 0;
    while (li < 3 && b >= bbase[li + 1]) ++li;
    return li;
}

__global__ __launch_bounds__(BTH) void k_chist4(BMeta a) {
    __shared__ int sc[1024];
    for (int i = threadIdx.x; i < 1024; i += BTH) sc[i] = 0;
    __syncthreads();
    int li = find_list(a.bbase, blockIdx.x);
    int lb = blockIdx.x - a.bbase[li];
    const int* dst = a.dst[li];
    int sh = a.shift[li];
    int b0 = lb * EPB;
    int end = min(b0 + EPB, a.E[li]);
    for (int i = b0 + threadIdx.x; i < end; i += BTH)
        atomicAdd(&sc[dst[i] >> sh], 1);
    __syncthreads();
    int* ccnt = a.ccnt[li];
    for (int i = threadIdx.x; i < 1024; i += BTH)
        if (sc[i]) atomicAdd(&ccnt[i], sc[i]);
}

__global__ __launch_bounds__(BTH) void k_cscat4(BMeta a) {
    __shared__ int scnt[1024];
    __shared__ int sbase[1024];
    for (int i = threadIdx.x; i < 1024; i += BTH) scnt[i] = 0;
    __syncthreads();
    int li = find_list(a.bbase, blockIdx.x);
    int lb = blockIdx.x - a.bbase[li];
    const int* src = a.src[li];
    const int* dst = a.dst[li];
    uint* pairs = a.pairs[li];
    int* ccur = a.ccur[li];
    int sh = a.shift[li];
    uint mask = (1u << sh) - 1u;
    int b0 = lb * EPB;
    int end = min(b0 + EPB, a.E[li]);
    for (int i = b0 + threadIdx.x; i < end; i += BTH)
        atomicAdd(&scnt[dst[i] >> sh], 1);
    __syncthreads();
    for (int i = threadIdx.x; i < 1024; i += BTH) {
        int c = scnt[i];
        sbase[i] = c ? atomicAdd(&ccur[i], c) : 0;
        scnt[i] = 0;
    }
    __syncthreads();
    for (int i = b0 + threadIdx.x; i < end; i += BTH) {
        int d = dst[i];
        int b = d >> sh;
        int p = sbase[b] + atomicAdd(&scnt[b], 1);
        pairs[p] = (uint)src[i] | (((uint)d & mask) << 20);
    }
}

struct CScan {
    const int* cnt[4]; int* base[4]; int* cur[4]; int* offNd[4];
    int nbk[4]; int E[4];
};
__global__ __launch_bounds__(1024) void k_cscan(CScan a) {
    int L = blockIdx.x;
    __shared__ int sm[1024];
    int t = threadIdx.x;
    int nbk = a.nbk[L];
    int v = (t < nbk) ? a.cnt[L][t] : 0;
    sm[t] = v;
    __syncthreads();
    for (int o = 1; o < 1024; o <<= 1) {
        int u = (t >= o) ? sm[t - o] : 0;
        __syncthreads();
        sm[t] += u;
        __syncthreads();
    }
    int excl = sm[t] - v;
    if (t < nbk) { a.base[L][t] = excl; a.cur[L][t] = excl; }
    if (t == nbk) a.base[L][t] = sm[1023];
    if (t == 0) a.offNd[L][0] = a.E[L];
}

struct FMeta {
    const uint* pairs[4]; const int* cbase[4];
    int* srt[4]; int* off[4];
    int shift[4]; int Nd[4]; int bbase[5];
};

__global__ __launch_bounds__(256) void k_fsort4(FMeta a) {
    int li = find_list(a.bbase, blockIdx.x);
    int b = blockIdx.x - a.bbase[li];
    const uint* pairs = a.pairs[li];
    const int* cbase = a.cbase[li];
    int* srt = a.srt[li];
    int* off = a.off[li];
    int shift = a.shift[li];
    int Nd = a.Nd[li];
    int p0 = cbase[b], p1 = cbase[b + 1];
    int width = 1 << shift;
    __shared__ int fcnt[256];
    __shared__ int fbase[256];
    __shared__ int sm[256];
    int t = threadIdx.x;
    fcnt[t] = 0;
    __syncthreads();
    for (int i = p0 + t; i < p1; i += 256)
        atomicAdd(&fcnt[pairs[i] >> 20], 1);
    __syncthreads();
    int v = fcnt[t];
    sm[t] = v;
    __syncthreads();
    for (int o = 1; o < 256; o <<= 1) {
        int u = (t >= o) ? sm[t - o] : 0;
        __syncthreads();
        sm[t] += u;
        __syncthreads();
    }
    int excl = sm[t] - v;
    fbase[t] = p0 + excl;
    int d0 = b << shift;
    if (t < width && d0 + t < Nd) off[d0 + t] = p0 + excl;
    fcnt[t] = 0;
    __syncthreads();
    for (int i = p0 + t; i < p1; i += 256) {
        uint pr = pairs[i];
        int loc = pr >> 20;
        int pos = fbase[loc] + atomicAdd(&fcnt[loc], 1);
        srt[pos] = (int)(pr & 0xFFFFFu);
    }
}

// ---------------- weight-vector prep: out[b][t] = sum_j M[b][t*64+j] * v[b][j] ----------------

struct WvN { const float* M[16]; const float* v[16]; int K[16]; };

__global__ __launch_bounds__(64) void k_wvN(WvN a, float* __restrict__ out) {
    int b = blockIdx.x, t = threadIdx.x;
    if (t < a.K[b]) {
        const float* M = a.M[b];
        const float* v = a.v[b];
        float s = 0.f;
        for (int j = 0; j < 64; ++j) s = fmaf(M[t * 64 + j], v[j], s);
        out[b * 64 + t] = s;
    }
}

// ---------------- row prep: es dots (+ optional bf16 copy, optional const add) ----------------
// 2 rows per wave (half-wave per row), K<=32.

struct PrepP {
    const float* X; int N;
    const float* v0; const float* v1; const float* v2;
    const float* c0; const float* c1;      // device scalars (K=1 results)
    ushort* xb;
    float* e0; float* e1; float* e2;
};

template <int K, int NDOT, bool WB, bool WC>
__global__ __launch_bounds__(256) void k_prep(PrepP a) {
    int wvid = (blockIdx.x * 256 + threadIdx.x) >> 6;
    int half = (threadIdx.x >> 5) & 1;
    int l32 = threadIdx.x & 31;
    int r = wvid * 2 + half;
    bool act = (r < a.N) && (l32 < K);
    float x = act ? a.X[(size_t)r * K + l32] : 0.f;
    if (WB && act) a.xb[(size_t)r * K + l32] = f2bf(x);
    float p0 = x * a.v0[l32 < K ? l32 : 0];
    float p1 = 0.f, p2 = 0.f;
    if (NDOT > 1) p1 = x * a.v1[l32 < K ? l32 : 0];
    if (NDOT > 2) p2 = x * a.v2[l32 < K ? l32 : 0];
    if (!act) { p0 = 0.f; p1 = 0.f; p2 = 0.f; }
#pragma unroll
    for (int o = 1; o < 32; o <<= 1) {
        p0 += __shfl_xor(p0, o, 64);
        if (NDOT > 1) p1 += __shfl_xor(p1, o, 64);
        if (NDOT > 2) p2 += __shfl_xor(p2, o, 64);
    }
    if (l32 == 0 && r < a.N) {
        a.e0[r] = p0 + (WC ? a.c0[0] : 0.f);
        if (NDOT > 1) a.e1[r] = p1 + (WC ? a.c1[0] : 0.f);
        if (NDOT > 2) a.e2[r] = p2;
    }
}

// ---------------- fused pull aggregation over raw bf16 features ----------------
// out[dst] = sum_e softmax(alpha)_e * pay[src_e]  (fp32 accumulate), zeros if no edges.
// Up to 3 relations per launch via block-range partition; one wave per dst row.

template <int D, int K>
struct AggP {
    const ushort* pay[3]; const float* es[3]; const float* xd[3];
    const float* wv[3]; const int* off[3]; const int* srt[3];
    float* out[3]; int Nd[3]; int bb[4];
};

template <int D, int K, int NR>
__global__ __launch_bounds__(256) void k_aggx(AggP<D, K> a) {
    int li = 0;
#pragma unroll
    for (int i = 1; i < NR; ++i)
        if ((int)blockIdx.x >= a.bb[i]) li = i;
    int wid = (blockIdx.x - a.bb[li]) * 4 + (threadIdx.x >> 6);
    int lane = threadIdx.x & 63;
    int Nd = a.Nd[li];
    if (wid >= Nd) return;
    const int* off = a.off[li];
    int s0 = off[wid], s1 = off[wid + 1];
    int n = s1 - s0;
    float* orow = a.out[li] + (size_t)wid * D;
    constexpr int L = (D == 16) ? 8 : 16;
    constexpr int G = 64 / L;
    int g = lane / L, l = lane % L;
    if (n <= 0) {
        if (lane < D) orow[lane] = 0.f;
        return;
    }
    const float* es = a.es[li];
    const int* srt = a.srt[li];
    const ushort* pay = a.pay[li];
    // ed (wave-uniform dst term)
    {
        const float* xd = a.xd[li];
        const float* wv = a.wv[li];
        float p = (lane < K) ? xd[(size_t)wid * K + lane] * wv[lane] : 0.f;
#pragma unroll
        for (int o = 32; o > 0; o >>= 1) p += __shfl_xor(p, o, 64);
        // sweep 1: gather es, cache idx + leaky logit (deg<=128 in regs), wave max
        float edj = p;
        int aidx0 = 0, aidx1 = 0;
        float ev0 = -3.4e38f, ev1 = -3.4e38f;
        if (lane < n) {
            aidx0 = srt[s0 + lane];
            float e = es[aidx0] + edj;
            ev0 = e > 0.f ? e : 0.2f * e;
        }
        if (lane + 64 < n) {
            aidx1 = srt[s0 + 64 + lane];
            float e = es[aidx1] + edj;
            ev1 = e > 0.f ? e : 0.2f * e;
        }
        float m = fmaxf(ev0, ev1);
        for (int i = s0 + 128 + lane; i < s1; i += 64) {
            float e = es[srt[i]] + edj;
            e = e > 0.f ? e : 0.2f * e;
            m = fmaxf(m, e);
        }
#pragma unroll
        for (int o = 32; o > 0; o >>= 1) m = fmaxf(m, __shfl_xor(m, o, 64));
        // convert cached logits to weights (exp leaves the inner loop)
        ev0 = (lane < n) ? __expf(ev0 - m) : 0.f;
        ev1 = (lane + 64 < n) ? __expf(ev1 - m) : 0.f;
        // sweep 2: L-lane group per edge, 2G edges per iteration
        float a0 = 0.f, a1 = 0.f, a2 = 0.f, a3 = 0.f, den = 0.f;
        for (int i = s0; i < s1; i += 2 * G) {
#pragma unroll
            for (int u = 0; u < 2; ++u) {
                int j = i + u * G + g;
                bool act = j < s1;
                int jj = j - s0;
                int idx = jj & 63;
                float wA = __shfl(ev0, idx, 64);
                float wB = __shfl(ev1, idx, 64);
                int iA = __shfl(aidx0, idx, 64);
                int iB = __shfl(aidx1, idx, 64);
                float w = (jj < 64) ? wA : wB;
                int s = (jj < 64) ? iA : iB;
                if (jj >= 128) {        // rare: deg > 128
                    s = srt[act ? j : s0];
                    float e = es[s] + edj;
                    e = e > 0.f ? e : 0.2f * e;
                    w = __expf(e - m);
                }
                if (!act) w = 0.f;
                den += w;
                if constexpr (D == 64) {
                    uint2 hv = ((const uint2*)(pay + (size_t)s * D))[l];
                    a0 = fmaf(w, bf_lo(hv.x), a0);
                    a1 = fmaf(w, bf_hi(hv.x), a1);
                    a2 = fmaf(w, bf_lo(hv.y), a2);
                    a3 = fmaf(w, bf_hi(hv.y), a3);
                } else {
                    uint hv = ((const uint*)(pay + (size_t)s * D))[l];
                    a0 = fmaf(w, bf_lo(hv), a0);
                    a1 = fmaf(w, bf_hi(hv), a1);
                }
            }
        }
#pragma unroll
        for (int o = L; o <= 32; o <<= 1) {
            a0 += __shfl_xor(a0, o, 64);
            a1 += __shfl_xor(a1, o, 64);
            if constexpr (D == 64) {
                a2 += __shfl_xor(a2, o, 64);
                a3 += __shfl_xor(a3, o, 64);
            }
            den += __shfl_xor(den, o, 64);
        }
        float inv = 1.f / (den + 1e-16f);
        if (g == 0) {
            if constexpr (D == 64) {
                float4 r = {a0 * inv, a1 * inv, a2 * inv, a3 * inv};
                ((float4*)orow)[l] = r;
            } else {
                float2 r = {a0 * inv, a1 * inv};
                ((float2*)orow)[l] = r;
            }
        }
    }
}

// ---------------- post-GEMMs on aggregates ----------------

// w1b = bf16(A @ W + b), A: [N,K] fp32
template <int K>
__global__ __launch_bounds__(256) void k_post1(const float* __restrict__ A,
                                               const float* __restrict__ W,
                                               const float* __restrict__ b,
                                               ushort* __restrict__ outb, int N) {
    int lane = threadIdx.x & 63;
    float wc[K];
#pragma unroll
    for (int k = 0; k < K; ++k) wc[k] = W[k * 64 + lane];
    float bl = b[lane];
    int w = (blockIdx.x * 256 + threadIdx.x) >> 6;
    int r0 = w * SRC_RPW, r1 = min(r0 + SRC_RPW, N);
    for (int r = r0; r < r1; ++r) {
        int ru = __builtin_amdgcn_readfirstlane(r);
        const float* xr = A + (size_t)ru * K;
        float acc0 = bl, acc1 = 0.f;
#pragma unroll
        for (int k = 0; k < K; k += 2) {
            acc0 = fmaf(xr[k], wc[k], acc0);
            acc1 = fmaf(xr[k + 1], wc[k + 1], acc1);
        }
        outb[(size_t)ru * 64 + lane] = f2bf(acc0 + acc1);
    }
}

// t1 = biasT1 + Ab@Wb + As@Ws + Ac@Wc   (fp32 out)
__global__ __launch_bounds__(256) void k_postt1(const float* __restrict__ Ab,
                                                const float* __restrict__ As,
                                                const float* __restrict__ Ac,
                                                const float* __restrict__ Wb,
                                                const float* __restrict__ Ws,
                                                const float* __restrict__ Wc,
                                                const float* __restrict__ bias,
                                                float* __restrict__ t1, int N) {
    int lane = threadIdx.x & 63;
    float wb[32], ws[32], wc[16];
#pragma unroll
    for (int k = 0; k < 32; ++k) wb[k] = Wb[k * 64 + lane];
#pragma unroll
    for (int k = 0; k < 32; ++k) ws[k] = Ws[k * 64 + lane];
#pragma unroll
    for (int k = 0; k < 16; ++k) wc[k] = Wc[k * 64 + lane];
    float bl = bias[lane];
    int w = (blockIdx.x * 256 + threadIdx.x) >> 6;
    int r0 = w * SRC_RPW, r1 = min(r0 + SRC_RPW, N);
    for (int r = r0; r < r1; ++r) {
        int ru = __builtin_amdgcn_readfirstlane(r);
        const float* rb = Ab + (size_t)ru * 32;
        const float* rs = As + (size_t)ru * 32;
        const float* rc = Ac + (size_t)ru * 16;
        float acc0 = bl, acc1 = 0.f;
#pragma unroll
        for (int k = 0; k < 32; k += 2) {
            acc0 = fmaf(rb[k], wb[k], acc0);
            acc1 = fmaf(rb[k + 1], wb[k + 1], acc1);
        }
#pragma unroll
        for (int k = 0; k < 32; k += 2) {
            acc0 = fmaf(rs[k], ws[k], acc0);
            acc1 = fmaf(rs[k + 1], ws[k + 1], acc1);
        }
#pragma unroll
        for (int k = 0; k < 16; k += 2) {
            acc0 = fmaf(rc[k], wc[k], acc0);
            acc1 = fmaf(rc[k + 1], wc[k + 1], acc1);
        }
        t1[(size_t)ru * 64 + lane] = acc0 + acc1;
    }
}

// out = (biasT2 + Ab@Wb + As@Ws) @ Wfc + bfc   -> [N,2]
__global__ __launch_bounds__(256) void k_postt2(const float* __restrict__ Ab,
                                                const float* __restrict__ As,
                                                const float* __restrict__ Wb,
                                                const float* __restrict__ Ws,
                                                const float* __restrict__ bias,
                                                const float* __restrict__ Wfc,
                                                const float* __restrict__ bfc,
                                                float* __restrict__ out, int N) {
    int lane = threadIdx.x & 63;
    float wb[64], ws[64];
#pragma unroll
    for (int k = 0; k < 64; ++k) wb[k] = Wb[k * 64 + lane];
#pragma unroll
    for (int k = 0; k < 64; ++k) ws[k] = Ws[k * 64 + lane];
    float bl = bias[lane];
    float f0 = Wfc[lane * 2 + 0], f1 = Wfc[lane * 2 + 1];
    float c0 = bfc[0], c1 = bfc[1];
    int w = (blockIdx.x * 256 + threadIdx.x) >> 6;
    int r0 = w * SRC_RPW, r1 = min(r0 + SRC_RPW, N);
    for (int r = r0; r < r1; ++r) {
        int ru = __builtin_amdgcn_readfirstlane(r);
        const float* rb = Ab + (size_t)ru * 64;
        const float* rs = As + (size_t)ru * 64;
        float acc0 = bl, acc1 = 0.f;
#pragma unroll
        for (int k = 0; k < 64; k += 2) {
            acc0 = fmaf(rb[k], wb[k], acc0);
            acc1 = fmaf(rb[k + 1], wb[k + 1], acc1);
        }
#pragma unroll
        for (int k = 0; k < 64; k += 2) {
            acc0 = fmaf(rs[k], ws[k], acc0);
            acc1 = fmaf(rs[k + 1], ws[k + 1], acc1);
        }
        float t2v = acc0 + acc1;
        float p0 = t2v * f0, p1 = t2v * f1;
#pragma unroll
        for (int o = 32; o > 0; o >>= 1) {
            p0 += __shfl_xor(p0, o, 64);
            p1 += __shfl_xor(p1, o, 64);
        }
        if (lane == 0) {
            out[ru * 2 + 0] = p0 + c0;
            out[ru * 2 + 1] = p1 + c1;
        }
    }
}

// ---------------- launcher ----------------

extern "C" void kernel_launch(void* const* d_in, const int* in_sizes, int n_in,
                              void* d_out, int out_size, void* d_ws, size_t ws_size,
                              hipStream_t stream) {
    const float* xw = (const float*)d_in[0];
    const float* xt = (const float*)d_in[1];
    const float* xd = (const float*)d_in[2];
    const float* g1ww_Ws = (const float*)d_in[3];
    const float* g1ww_Wd = (const float*)d_in[4];
    const float* g1ww_as = (const float*)d_in[5];
    const float* g1ww_ad = (const float*)d_in[6];
    const float* g1ww_b  = (const float*)d_in[7];
    const float* g1bu_Ws = (const float*)d_in[8];
    const float* g1bu_Wd = (const float*)d_in[9];
    const float* g1bu_as = (const float*)d_in[10];
    const float* g1bu_ad = (const float*)d_in[11];
    const float* g1bu_b  = (const float*)d_in[12];
    const float* g1se_Ws = (const float*)d_in[13];
    const float* g1se_Wd = (const float*)d_in[14];
    const float* g1se_as = (const float*)d_in[15];
    const float* g1se_ad = (const float*)d_in[16];
    const float* g1se_b  = (const float*)d_in[17];
    const float* g1cr_Ws = (const float*)d_in[18];
    const float* g1cr_Wd = (const float*)d_in[19];
    const float* g1cr_as = (const float*)d_in[20];
    const float* g1cr_ad = (const float*)d_in[21];
    const float* g1cr_b  = (const float*)d_in[22];
    // d_in[23..27] = g2ww params: w2 dead in reference -> skipped
    const float* g2bu_Ws = (const float*)d_in[28];
    const float* g2bu_Wd = (const float*)d_in[29];
    const float* g2bu_as = (const float*)d_in[30];
    const float* g2bu_ad = (const float*)d_in[31];
    const float* g2bu_b  = (const float*)d_in[32];
    const float* g2se_Ws = (const float*)d_in[33];
    const float* g2se_Wd = (const float*)d_in[34];
    const float* g2se_as = (const float*)d_in[35];
    const float* g2se_ad = (const float*)d_in[36];
    const float* g2se_b  = (const float*)d_in[37];
    const float* Wfc = (const float*)d_in[38];
    const float* bfc = (const float*)d_in[39];
    const int* ww_src = (const int*)d_in[40];
    const int* ww_dst = (const int*)d_in[41];
    const int* bu_src = (const int*)d_in[42];
    const int* bu_dst = (const int*)d_in[43];
    const int* se_src = (const int*)d_in[44];
    const int* se_dst = (const int*)d_in[45];
    const int* cr_src = (const int*)d_in[46];
    const int* cr_dst = (const int*)d_in[47];

    const int totalE = EWW + EBU + ESE + ECR;

    // ---- workspace carve ----
    char* p = (char*)d_ws;
    auto alloc = [&](size_t bytes) {
        char* r = p;
        p += (bytes + 255) & ~(size_t)255;
        return r;
    };
    // pairs (build-only, 14.5 MB) aliases ax_ww + ax_bu (written only after fsort)
    size_t axww_b = ((size_t)NW * 32 * 4 + 255) & ~(size_t)255;
    size_t axbu_b = ((size_t)NT * 32 * 4 + 255) & ~(size_t)255;
    size_t pairs_b = ((size_t)totalE * 4 + 255) & ~(size_t)255;
    size_t r1_b = axww_b + axbu_b;
    if (pairs_b > r1_b) r1_b = pairs_b;
    char* r1 = alloc(r1_b);
    float* ax_ww = (float*)r1;
    float* ax_bu = (float*)(r1 + axww_b);
    uint* pairsW = (uint*)r1;
    uint* pairsB = pairsW + EWW;
    uint* pairsS = pairsB + EBU;
    uint* pairsC = pairsS + ESE;

    ushort* xwb  = (ushort*)alloc((size_t)NW * 32 * 2);
    ushort* xdb  = (ushort*)alloc((size_t)ND * 16 * 2);
    ushort* w1b  = (ushort*)alloc((size_t)NW * 64 * 2);
    float* ax_se = (float*)alloc((size_t)NT * 32 * 4);
    float* ax_cr = (float*)alloc((size_t)NT * 16 * 4);
    float* ax2bu = (float*)alloc((size_t)NT * 64 * 4);
    float* ax2se = (float*)alloc((size_t)NT * 64 * 4);
    float* t1    = (float*)alloc((size_t)NT * 64 * 4);
    float* esww  = (float*)alloc((size_t)NW * 4);
    float* esbu  = (float*)alloc((size_t)NW * 4);
    float* esse  = (float*)alloc((size_t)NW * 4);
    float* escr  = (float*)alloc((size_t)ND * 4);
    float* es2bu = (float*)alloc((size_t)NW * 4);
    float* es2se = (float*)alloc((size_t)NW * 4);
    float* wvbuf = (float*)alloc(16 * 64 * 4);
    float* biasT1 = (float*)alloc(64 * 4);
    float* biasT2 = (float*)alloc(64 * 4);
    int* ccnt  = (int*)alloc(4 * 1024 * 4);
    int* cbase = (int*)alloc(4 * 1025 * 4);
    int* ccur  = (int*)alloc(4 * 1024 * 4);
    int* offW = (int*)alloc((size_t)(NW + 1) * 4);
    int* offB = (int*)alloc((size_t)(NT + 1) * 4);
    int* offS = (int*)alloc((size_t)(NT + 1) * 4);
    int* offC = (int*)alloc((size_t)(NT + 1) * 4);
    int* srtW = (int*)alloc((size_t)EWW * 4);
    int* srtB = (int*)alloc((size_t)EBU * 4);
    int* srtS = (int*)alloc((size_t)ESE * 4);
    int* srtC = (int*)alloc((size_t)ECR * 4);

    const int thr = 256;
    const int SHW = 8, NBW = (NW + 255) / 256;
    const int SHT = 6, NBT = (NT + 63) / 64;
    const int RPB = SRC_RPW * 4;

    const int nbW = (EWW + EPB - 1) / EPB;
    const int nbB = (EBU + EPB - 1) / EPB;
    const int nbS = (ESE + EPB - 1) / EPB;
    const int nbC = (ECR + EPB - 1) / EPB;
    const int nbTot = nbW + nbB + nbS + nbC;

    // ---- CSR build ----
    k_zero<<<(4 * 1024 + thr - 1) / thr, thr, 0, stream>>>(ccnt, 4 * 1024);

    BMeta bm;
    bm.src[0] = ww_src; bm.dst[0] = ww_dst; bm.ccnt[0] = ccnt + 0 * 1024; bm.ccur[0] = ccur + 0 * 1024;
    bm.pairs[0] = pairsW; bm.E[0] = EWW; bm.shift[0] = SHW;
    bm.src[1] = bu_src; bm.dst[1] = bu_dst; bm.ccnt[1] = ccnt + 1 * 1024; bm.ccur[1] = ccur + 1 * 1024;
    bm.pairs[1] = pairsB; bm.E[1] = EBU; bm.shift[1] = SHT;
    bm.src[2] = se_src; bm.dst[2] = se_dst; bm.ccnt[2] = ccnt + 2 * 1024; bm.ccur[2] = ccur + 2 * 1024;
    bm.pairs[2] = pairsS; bm.E[2] = ESE; bm.shift[2] = SHT;
    bm.src[3] = cr_src; bm.dst[3] = cr_dst; bm.ccnt[3] = ccnt + 3 * 1024; bm.ccur[3] = ccur + 3 * 1024;
    bm.pairs[3] = pairsC; bm.E[3] = ECR; bm.shift[3] = SHT;
    bm.bbase[0] = 0; bm.bbase[1] = nbW; bm.bbase[2] = nbW + nbB;
    bm.bbase[3] = nbW + nbB + nbS; bm.bbase[4] = nbTot;

    k_chist4<<<nbTot, BTH, 0, stream>>>(bm);

    CScan cs;
    cs.cnt[0] = ccnt + 0 * 1024; cs.base[0] = cbase + 0 * 1025; cs.cur[0] = ccur + 0 * 1024;
    cs.offNd[0] = offW + NW; cs.nbk[0] = NBW; cs.E[0] = EWW;
    cs.cnt[1] = ccnt + 1 * 1024; cs.base[1] = cbase + 1 * 1025; cs.cur[1] = ccur + 1 * 1024;
    cs.offNd[1] = offB + NT; cs.nbk[1] = NBT; cs.E[1] = EBU;
    cs.cnt[2] = ccnt + 2 * 1024; cs.base[2] = cbase + 2 * 1025; cs.cur[2] = ccur + 2 * 1024;
    cs.offNd[2] = offS + NT; cs.nbk[2] = NBT; cs.E[2] = ESE;
    cs.cnt[3] = ccnt + 3 * 1024; cs.base[3] = cbase + 3 * 1025; cs.cur[3] = ccur + 3 * 1024;
    cs.offNd[3] = offC + NT; cs.nbk[3] = NBT; cs.E[3] = ECR;
    k_cscan<<<4, 1024, 0, stream>>>(cs);

    k_cscat4<<<nbTot, BTH, 0, stream>>>(bm);

    FMeta fm;
    fm.pairs[0] = pairsW; fm.cbase[0] = cbase + 0 * 1025; fm.srt[0] = srtW; fm.off[0] = offW;
    fm.shift[0] = SHW; fm.Nd[0] = NW;
    fm.pairs[1] = pairsB; fm.cbase[1] = cbase + 1 * 1025; fm.srt[1] = srtB; fm.off[1] = offB;
    fm.shift[1] = SHT; fm.Nd[1] = NT;
    fm.pairs[2] = pairsS; fm.cbase[2] = cbase + 2 * 1025; fm.srt[2] = srtS; fm.off[2] = offS;
    fm.shift[2] = SHT; fm.Nd[2] = NT;
    fm.pairs[3] = pairsC; fm.cbase[3] = cbase + 3 * 1025; fm.srt[3] = srtC; fm.off[3] = offC;
    fm.shift[3] = SHT; fm.Nd[3] = NT;
    fm.bbase[0] = 0; fm.bbase[1] = NBW; fm.bbase[2] = NBW + NBT;
    fm.bbase[3] = NBW + 2 * NBT; fm.bbase[4] = NBW + 3 * NBT;
    k_fsort4<<<NBW + 3 * NBT, thr, 0, stream>>>(fm);

    // ---- weight-vector prep ----
    // rows 0-5: wv (Wd@a_d) for ed; rows 6-11: ws (Ws@a_s) for es
    WvN wa;
    wa.M[0] = g1ww_Wd; wa.v[0] = g1ww_ad; wa.K[0] = 32;
    wa.M[1] = g1bu_Wd; wa.v[1] = g1bu_ad; wa.K[1] = 32;
    wa.M[2] = g1se_Wd; wa.v[2] = g1se_ad; wa.K[2] = 32;
    wa.M[3] = g1cr_Wd; wa.v[3] = g1cr_ad; wa.K[3] = 32;
    wa.M[4] = g2bu_Wd; wa.v[4] = g2bu_ad; wa.K[4] = 64;
    wa.M[5] = g2se_Wd; wa.v[5] = g2se_ad; wa.K[5] = 64;
    wa.M[6] = g1ww_Ws; wa.v[6] = g1ww_as; wa.K[6] = 32;
    wa.M[7] = g1bu_Ws; wa.v[7] = g1bu_as; wa.K[7] = 32;
    wa.M[8] = g1se_Ws; wa.v[8] = g1se_as; wa.K[8] = 32;
    wa.M[9] = g1cr_Ws; wa.v[9] = g1cr_as; wa.K[9] = 16;
    wa.M[10] = g2bu_Ws; wa.v[10] = g2bu_as; wa.K[10] = 64;
    wa.M[11] = g2se_Ws; wa.v[11] = g2se_as; wa.K[11] = 64;
    k_wvN<<<12, 64, 0, stream>>>(wa, wvbuf);
    // rows 12-15: vb_bu = Ws_ww@ws2_bu, vb_se, cb_bu = b_ww . ws2_bu, cb_se
    WvN wb2;
    wb2.M[0] = g1ww_Ws; wb2.v[0] = wvbuf + 10 * 64; wb2.K[0] = 32;
    wb2.M[1] = g1ww_Ws; wb2.v[1] = wvbuf + 11 * 64; wb2.K[1] = 32;
    wb2.M[2] = g1ww_b;  wb2.v[2] = wvbuf + 10 * 64; wb2.K[2] = 1;
    wb2.M[3] = g1ww_b;  wb2.v[3] = wvbuf + 11 * 64; wb2.K[3] = 1;
    k_wvN<<<4, 64, 0, stream>>>(wb2, wvbuf + 12 * 64);
    k_bsum<<<1, 64, 0, stream>>>(g1bu_b, g1se_b, g1cr_b, biasT1);
    k_bsum<<<1, 64, 0, stream>>>(g2bu_b, g2se_b, nullptr, biasT2);

    // ---- feature prep: bf16 copies + src logits ----
    PrepP pw;
    pw.X = xw; pw.N = NW;
    pw.v0 = wvbuf + 6 * 64; pw.v1 = wvbuf + 7 * 64; pw.v2 = wvbuf + 8 * 64;
    pw.c0 = nullptr; pw.c1 = nullptr;
    pw.xb = xwb; pw.e0 = esww; pw.e1 = esbu; pw.e2 = esse;
    k_prep<32, 3, true, false><<<(NW / 2 + 3) / 4 + 1, thr, 0, stream>>>(pw);
    PrepP pd;
    pd.X = xd; pd.N = ND;
    pd.v0 = wvbuf + 9 * 64; pd.v1 = nullptr; pd.v2 = nullptr;
    pd.c0 = nullptr; pd.c1 = nullptr;
    pd.xb = xdb; pd.e0 = escr; pd.e1 = nullptr; pd.e2 = nullptr;
    k_prep<16, 1, true, false><<<(ND / 2 + 3) / 4 + 1, thr, 0, stream>>>(pd);

    // ---- layer 1 fused aggregation (ww + bu + se over xwb) ----
    const int nbAw = (NW + 3) / 4, nbAt = (NT + 3) / 4;
    AggP<32, 32> a1;
    a1.pay[0] = xwb; a1.es[0] = esww; a1.xd[0] = xw; a1.wv[0] = wvbuf + 0 * 64;
    a1.off[0] = offW; a1.srt[0] = srtW; a1.out[0] = ax_ww; a1.Nd[0] = NW;
    a1.pay[1] = xwb; a1.es[1] = esbu; a1.xd[1] = xt; a1.wv[1] = wvbuf + 1 * 64;
    a1.off[1] = offB; a1.srt[1] = srtB; a1.out[1] = ax_bu; a1.Nd[1] = NT;
    a1.pay[2] = xwb; a1.es[2] = esse; a1.xd[2] = xt; a1.wv[2] = wvbuf + 2 * 64;
    a1.off[2] = offS; a1.srt[2] = srtS; a1.out[2] = ax_se; a1.Nd[2] = NT;
    a1.bb[0] = 0; a1.bb[1] = nbAw; a1.bb[2] = nbAw + nbAt; a1.bb[3] = nbAw + 2 * nbAt;
    k_aggx<32, 32, 3><<<nbAw + 2 * nbAt, thr, 0, stream>>>(a1);

    // cr (tiny, D=16)
    AggP<16, 32> ac;
    ac.pay[0] = xdb; ac.es[0] = escr; ac.xd[0] = xt; ac.wv[0] = wvbuf + 3 * 64;
    ac.off[0] = offC; ac.srt[0] = srtC; ac.out[0] = ax_cr; ac.Nd[0] = NT;
    ac.pay[1] = nullptr; ac.es[1] = nullptr; ac.xd[1] = nullptr; ac.wv[1] = nullptr;
    ac.off[1] = nullptr; ac.srt[1] = nullptr; ac.out[1] = nullptr; ac.Nd[1] = 0;
    ac.pay[2] = nullptr; ac.es[2] = nullptr; ac.xd[2] = nullptr; ac.wv[2] = nullptr;
    ac.off[2] = nullptr; ac.srt[2] = nullptr; ac.out[2] = nullptr; ac.Nd[2] = 0;
    ac.bb[0] = 0; ac.bb[1] = nbAt; ac.bb[2] = nbAt; ac.bb[3] = nbAt;
    k_aggx<16, 32, 1><<<nbAt, thr, 0, stream>>>(ac);

    // ---- post-GEMMs: w1b + es2, t1 ----
    k_post1<32><<<(NW + RPB - 1) / RPB, thr, 0, stream>>>(ax_ww, g1ww_Ws, g1ww_b, w1b, NW);
    PrepP p2;
    p2.X = ax_ww; p2.N = NW;
    p2.v0 = wvbuf + 12 * 64; p2.v1 = wvbuf + 13 * 64; p2.v2 = nullptr;
    p2.c0 = wvbuf + 14 * 64; p2.c1 = wvbuf + 15 * 64;
    p2.xb = nullptr; p2.e0 = es2bu; p2.e1 = es2se; p2.e2 = nullptr;
    k_prep<32, 2, false, true><<<(NW / 2 + 3) / 4 + 1, thr, 0, stream>>>(p2);
    k_postt1<<<(NT + RPB - 1) / RPB, thr, 0, stream>>>(ax_bu, ax_se, ax_cr,
                                                       g1bu_Ws, g1se_Ws, g1cr_Ws,
                                                       biasT1, t1, NT);

    // ---- layer 2 fused aggregation (bu + se over w1b) ----
    AggP<64, 64> a2;
    a2.pay[0] = w1b; a2.es[0] = es2bu; a2.xd[0] = t1; a2.wv[0] = wvbuf + 4 * 64;
    a2.off[0] = offB; a2.srt[0] = srtB; a2.out[0] = ax2bu; a2.Nd[0] = NT;
    a2.pay[1] = w1b; a2.es[1] = es2se; a2.xd[1] = t1; a2.wv[1] = wvbuf + 5 * 64;
    a2.off[1] = offS; a2.srt[1] = srtS; a2.out[1] = ax2se; a2.Nd[1] = NT;
    a2.pay[2] = nullptr; a2.es[2] = nullptr; a2.xd[2] = nullptr; a2.wv[2] = nullptr;
    a2.off[2] = nullptr; a2.srt[2] = nullptr; a2.out[2] = nullptr; a2.Nd[2] = 0;
    a2.bb[0] = 0; a2.bb[1] = nbAt; a2.bb[2] = 2 * nbAt; a2.bb[3] = 2 * nbAt;
    k_aggx<64, 64, 2><<<2 * nbAt, thr, 0, stream>>>(a2);

    // ---- final: t2 + FC fused ----
    k_postt2<<<(NT + RPB - 1) / RPB, thr, 0, stream>>>(ax2bu, ax2se, g2bu_Ws, g2se_Ws,
                                                       biasT2, Wfc, bfc, (float*)d_out, NT);
}